// Round 8
// baseline (807.481 us; speedup 1.0000x reference)
//
#include <hip/hip_runtime.h>
#include <hip/hip_bf16.h>
#include <hip/hip_fp8.h>

#define N_NODES   100000
#define N_EDGES   1600000
#define NUM_GRAPHS 1024
#define D         128
#define LN_EPS    1e-5f
#define NBUCKETS  391     // buckets of 256 nodes: bucket = dst >> 8
#define CAP       4864    // fixed bucket capacity (mean 4096 + 12 sigma); CAP/256 = 19
#define CHUNK     4096    // edges per bin_scatter block

typedef __attribute__((ext_vector_type(8))) short short8;
typedef __attribute__((ext_vector_type(4))) float floatx4;
typedef __attribute__((ext_vector_type(2))) float f32x2;

static __device__ __forceinline__ unsigned short f2bf(float f) {
    __hip_bfloat16 h = __float2bfloat16(f);
    return *reinterpret_cast<unsigned short*>(&h);
}
static __device__ __forceinline__ unsigned char fp8b(float v) {
    __hip_fp8_e4m3 t = (__hip_fp8_e4m3)v;
    return *reinterpret_cast<unsigned char*>(&t);
}
// accumulate 8 bf16 channels (one uint4) into 4 packed fp32 pairs
static __device__ __forceinline__ void acc4(f32x2* acc, uint4 v) {
    acc[0] += (f32x2){__uint_as_float(v.x << 16), __uint_as_float(v.x & 0xffff0000u)};
    acc[1] += (f32x2){__uint_as_float(v.y << 16), __uint_as_float(v.y & 0xffff0000u)};
    acc[2] += (f32x2){__uint_as_float(v.z << 16), __uint_as_float(v.z & 0xffff0000u)};
    acc[3] += (f32x2){__uint_as_float(v.w << 16), __uint_as_float(v.w & 0xffff0000u)};
}

// ---- fp8 e4m3 (OCP) pack/unpack ----
#if __has_builtin(__builtin_amdgcn_cvt_pk_f32_fp8)
#define UNPK_FP8(x, w) __builtin_amdgcn_cvt_pk_f32_fp8((x), (w))
#else
static __device__ __forceinline__ f32x2 unpk_fp8_sw(unsigned x, bool w) {
    unsigned s = w ? (x >> 16) : (x & 0xffffu);
    __hip_fp8_e4m3 a, b;
    *reinterpret_cast<unsigned char*>(&a) = (unsigned char)(s & 0xff);
    *reinterpret_cast<unsigned char*>(&b) = (unsigned char)((s >> 8) & 0xff);
    return (f32x2){(float)a, (float)b};
}
#define UNPK_FP8(x, w) unpk_fp8_sw((x), (w))
#endif

#if __has_builtin(__builtin_amdgcn_cvt_pk_fp8_f32)
#define PK_FP8(a, b, old, w) ((unsigned)__builtin_amdgcn_cvt_pk_fp8_f32((a), (b), (int)(old), (w)))
#else
static __device__ __forceinline__ unsigned pk_fp8_sw(float a, float b) {
    __hip_fp8_e4m3 fa = (__hip_fp8_e4m3)a;
    __hip_fp8_e4m3 fb = (__hip_fp8_e4m3)b;
    return (unsigned)*reinterpret_cast<unsigned char*>(&fa) |
           ((unsigned)*reinterpret_cast<unsigned char*>(&fb) << 8);
}
#define PK_FP8(a, b, old, w) ((w) ? ((((unsigned)(old)) & 0xffffu) | (pk_fp8_sw((a),(b)) << 16)) \
                                  : ((((unsigned)(old)) & 0xffff0000u) | pk_fp8_sw((a),(b))))
#endif

// async 16B global->LDS; lds ptr must be wave-uniform base (HW adds lane*16)
#define GLOAD16(g, l) __builtin_amdgcn_global_load_lds( \
    (const __attribute__((address_space(1))) void*)(g), \
    (__attribute__((address_space(3))) void*)(l), 16, 0, 0)

// ---- fused prep: x -> bf16 + fp8 tables, weight concat+cvt, cursor init ----
__global__ __launch_bounds__(256)
void prep_kernel(const float* __restrict__ x, unsigned short* __restrict__ xbf,
                 unsigned* __restrict__ xf8,
                 const float* __restrict__ W1l, const float* __restrict__ W1r,
                 const float* __restrict__ W2l, const float* __restrict__ W2r,
                 unsigned short* __restrict__ Wc1, unsigned short* __restrict__ Wc2,
                 int* __restrict__ cursor, int* __restrict__ dhist) {
    int i = blockIdx.x * 256 + threadIdx.x;     // float4 index, 3.2M exact
    float4 v = reinterpret_cast<const float4*>(x)[i];
    ushort4 o;
    o.x = f2bf(v.x); o.y = f2bf(v.y); o.z = f2bf(v.z); o.w = f2bf(v.w);
    reinterpret_cast<ushort4*>(xbf)[i] = o;
    unsigned p = PK_FP8(v.x, v.y, 0u, false);
    p = PK_FP8(v.z, v.w, p, true);
    xf8[i] = p;                                 // 4 fp8 bytes, coalesced
    if (blockIdx.x < 256) {                     // 65536 weight elements
        int layer = i >> 15;
        int rem = i & 32767;
        int c = rem >> 8;
        int k = rem & 255;
        const float* Wl = layer ? W2l : W1l;
        const float* Wr = layer ? W2r : W1r;
        unsigned short* dst = layer ? Wc2 : Wc1;
        float wv = (k < 128) ? Wl[c * 128 + k] : Wr[c * 128 + (k - 128)];
        dst[c * 256 + k] = f2bf(wv);
    }
    if (blockIdx.x == 256) {
        for (int b = threadIdx.x; b < NBUCKETS; b += 256)
            cursor[b] = b * CAP;
        // zero dummy row N_NODES of the fp8 table (degree padding target)
        if (threadIdx.x < 32)
            xf8[(size_t)N_NODES * 32 + threadIdx.x] = 0u;
        if (threadIdx.x < 128)                  // dhist[64] + dcur[64]
            dhist[threadIdx.x] = 0;
    }
}

// ---- scatter edges into fixed-capacity dst buckets; 4B packed records ----
// rec = (dst&255)<<17 | src   (src < 2^17)
__global__ __launch_bounds__(256)
void bin_scatter_kernel(const int* __restrict__ src, const int* __restrict__ dst,
                        int* __restrict__ cursor, unsigned* __restrict__ binned) {
    __shared__ int cnt[NBUCKETS];
    __shared__ int base[NBUCKETS];
    int chunkBase = blockIdx.x * CHUNK;
    for (int i = threadIdx.x; i < NBUCKETS; i += 256) cnt[i] = 0;
    __syncthreads();
    int es[16], ed[16], lofs[16];
    #pragma unroll
    for (int j = 0; j < 16; ++j) {
        int e = chunkBase + j * 256 + threadIdx.x;
        if (e < N_EDGES) {
            es[j] = src[e];
            ed[j] = dst[e];
            lofs[j] = atomicAdd(&cnt[ed[j] >> 8], 1);
        }
    }
    __syncthreads();
    for (int i = threadIdx.x; i < NBUCKETS; i += 256) {
        int c = cnt[i];
        base[i] = c ? atomicAdd(&cursor[i], c) : 0;
    }
    __syncthreads();
    #pragma unroll
    for (int j = 0; j < 16; ++j) {
        int e = chunkBase + j * 256 + threadIdx.x;
        if (e < N_EDGES) {
            int b = ed[j] >> 8;
            int pos = base[b] + lofs[j];
            if (pos < (b + 1) * CAP)            // capacity guard (never hit at 12 sigma)
                binned[pos] = ((unsigned)(ed[j] & 255) << 17) | (unsigned)es[j];
        }
    }
}

// One block per bucket (256 nodes), single pass: records + ranks in registers.
// Also feeds the global degree histogram (64 bins) for the perm sort.
__global__ __launch_bounds__(256)
void bucket_build_kernel(const unsigned* __restrict__ binned, const int* __restrict__ cursor,
                         int2* __restrict__ row_info, int* __restrict__ src_sorted,
                         int* __restrict__ dhist) {
    __shared__ int scnt[256];
    __shared__ int sscan[256];
    int b = blockIdx.x;
    int t = threadIdx.x;
    int lo = b * CAP;
    int hi = cursor[b];
    int cap_end = lo + CAP;
    if (hi > cap_end) hi = cap_end;
    scnt[t] = 0;
    __syncthreads();
    unsigned rec[19];
    short rnk[19];
    #pragma unroll
    for (int i = 0; i < 19; ++i) {
        int e = lo + t + i * 256;
        if (e < hi) {
            unsigned r = binned[e];
            rec[i] = r;
            rnk[i] = (short)atomicAdd(&scnt[r >> 17], 1);
        }
    }
    __syncthreads();
    int v = scnt[t];
    sscan[t] = v;
    __syncthreads();
    for (int off = 1; off < 256; off <<= 1) {
        int a = (t >= off) ? sscan[t - off] : 0;
        __syncthreads();
        sscan[t] += a;
        __syncthreads();
    }
    int ex = sscan[t] - v;
    int node = b * 256 + t;
    if (node < N_NODES) {
        row_info[node] = make_int2(lo + ex, v);
        atomicAdd(&dhist[v < 63 ? v : 63], 1);
    }
    scnt[t] = ex;
    __syncthreads();
    #pragma unroll
    for (int i = 0; i < 19; ++i) {
        int e = lo + t + i * 256;
        if (e < hi) {
            unsigned r = rec[i];
            src_sorted[lo + scnt[r >> 17] + rnk[i]] = (int)(r & 0x1FFFFu);
        }
    }
}

// ---- degree counting-sort scatter: perm[pos] = node, pos by degree bin ----
// Each block redundantly scans the 64-bin histogram (consistent across blocks),
// then global-atomics into per-bin cursors for unique positions.
__global__ __launch_bounds__(256)
void perm_kernel(const int2* __restrict__ row_info, const int* __restrict__ dhist,
                 int* __restrict__ dcur, int* __restrict__ perm) {
    __shared__ int sc[64];
    int t = threadIdx.x;
    if (t < 64) sc[t] = dhist[t];
    __syncthreads();
    for (int off = 1; off < 64; off <<= 1) {
        int a = (t < 64 && t >= off) ? sc[t - off] : 0;
        __syncthreads();
        if (t < 64) sc[t] += a;
        __syncthreads();
    }
    int node = blockIdx.x * 256 + t;
    if (node < N_NODES) {
        int dg = row_info[node].y;
        int bin = dg < 63 ? dg : 63;
        int base = bin ? sc[bin - 1] : 0;
        int pos = base + atomicAdd(&dcur[bin], 1);
        perm[pos] = node;
    }
}

// ---- mean aggregation from fp8 table ----
// 4 nodes per wave via degree-sorted perm (co-scheduled nodes have ~equal
// degree -> dmax padding ~0). 16-lane group per node, lane owns 8 channels.
// Out-of-degree rounds cndmask-redirect to the zeroed dummy row N_NODES ->
// no masks, no tails, no cross-lane reduction, no LDS.
__global__ __launch_bounds__(256)
void aggregate_kernel(const unsigned char* __restrict__ feat8,
                      const int* __restrict__ src_sorted,
                      const int2* __restrict__ row_info,
                      const int* __restrict__ perm,
                      unsigned short* __restrict__ aggout) {
    int tid  = threadIdx.x;
    int wave = tid >> 6;
    int lane = tid & 63;
    int l16  = lane & 15;                       // channel octet within row
    int grpbase = lane & 48;                    // (lane>>4)*16
    int node = perm[blockIdx.x * 16 + wave * 4 + (lane >> 4)];  // 6250*16 = 100000
    int2 ri = row_info[node];
    int s = ri.x, deg = ri.y;
    // wave-uniform max degree across the 4 groups (near-equal after sort)
    int dmax = deg;
    dmax = max(dmax, __shfl_xor(dmax, 16, 64));
    dmax = max(dmax, __shfl_xor(dmax, 32, 64));
    unsigned chb = (unsigned)l16 * 8;           // byte offset within 128B row
    f32x2 a0[4], a1[4];
    #pragma unroll
    for (int i = 0; i < 4; ++i) { a0[i] = (f32x2){0.f, 0.f}; a1[i] = (f32x2){0.f, 0.f}; }

    for (int c0 = 0; c0 < dmax; c0 += 16) {
        int si = src_sorted[s + c0 + l16];      // group's edges c0..c0+15 (may read slack)
        int rel = deg - c0;                     // per-lane valid-round bound
        int rend = dmax - c0; if (rend > 16) rend = 16;
        int r = 0;
        for (; r + 2 <= rend; r += 2) {
            int u0 = __shfl(si, grpbase + r, 64);
            int u1 = __shfl(si, grpbase + r + 1, 64);
            u0 = (r < rel) ? u0 : N_NODES;
            u1 = (r + 1 < rel) ? u1 : N_NODES;
            uint2 v0 = *(const uint2*)(feat8 + (((unsigned)u0 << 7) + chb));
            uint2 v1 = *(const uint2*)(feat8 + (((unsigned)u1 << 7) + chb));
            a0[0] += UNPK_FP8(v0.x, false);
            a0[1] += UNPK_FP8(v0.x, true);
            a0[2] += UNPK_FP8(v0.y, false);
            a0[3] += UNPK_FP8(v0.y, true);
            a1[0] += UNPK_FP8(v1.x, false);
            a1[1] += UNPK_FP8(v1.x, true);
            a1[2] += UNPK_FP8(v1.y, false);
            a1[3] += UNPK_FP8(v1.y, true);
        }
        if (r < rend) {
            int u0 = __shfl(si, grpbase + r, 64);
            u0 = (r < rel) ? u0 : N_NODES;
            uint2 v0 = *(const uint2*)(feat8 + (((unsigned)u0 << 7) + chb));
            a0[0] += UNPK_FP8(v0.x, false);
            a0[1] += UNPK_FP8(v0.x, true);
            a0[2] += UNPK_FP8(v0.y, false);
            a0[3] += UNPK_FP8(v0.y, true);
        }
    }
    float inv = 1.f / (float)(deg > 1 ? deg : 1);
    f32x2 t0 = (a0[0] + a1[0]) * inv;
    f32x2 t1 = (a0[1] + a1[1]) * inv;
    f32x2 t2 = (a0[2] + a1[2]) * inv;
    f32x2 t3 = (a0[3] + a1[3]) * inv;
    uint4 o;
    o.x = (unsigned)f2bf(t0.x) | ((unsigned)f2bf(t0.y) << 16);
    o.y = (unsigned)f2bf(t1.x) | ((unsigned)f2bf(t1.y) << 16);
    o.z = (unsigned)f2bf(t2.x) | ((unsigned)f2bf(t2.y) << 16);
    o.w = (unsigned)f2bf(t3.x) | ((unsigned)f2bf(t3.y) << 16);
    *(uint4*)(aggout + (size_t)node * 128 + l16 * 8) = o;
}

// ---- fused SAGE linear: relu([A1|A2]@Wcat^T+b), bf16 MFMA ----
// T3 minimum-2-phase, 64-node tile (R6-verified). Optional fused fp8 output
// (layer 1) replaces the separate cvt pass. Swizzle per rule #21.
__global__ __launch_bounds__(256)
void gemm_kernel(const unsigned short* __restrict__ A1,   // k 0..127   (agg)
                 const unsigned short* __restrict__ A2,   // k 128..255 (self)
                 const unsigned short* __restrict__ Wcat, // [128 cols][256 k] bf16
                 const float* __restrict__ bias,
                 unsigned short* __restrict__ out,
                 unsigned char* __restrict__ f8out) {
    __shared__ unsigned char sm[2][12288];    // [buf][A 4KB | W 8KB]
    int tid  = threadIdx.x;
    int w    = tid >> 6;
    int lane = tid & 63;
    int quad = lane >> 4, m = lane & 15;
    int nodeBase = blockIdx.x * 64;
    int gm = (m & 3) ^ ((m >> 2) & 3);        // per-thread read-swizzle constant
    int qo = ((quad ^ gm) & 3) * 16;          // swizzled 16B-unit byte offset

    int arow = w * 16 + (lane >> 2);
    int ga   = (arow & 3) ^ ((arow >> 2) & 3);
    int ua   = (lane & 3) ^ ga;
    int ra   = nodeBase + arow; if (ra > N_NODES - 1) ra = N_NODES - 1;
    int col0 = w * 32 + (lane >> 2);
    int col1 = col0 + 16;
    int u0 = (lane & 3) ^ ((col0 & 3) ^ ((col0 >> 2) & 3));
    int u1 = (lane & 3) ^ ((col1 & 3) ^ ((col1 >> 2) & 3));
    const char* a1c = (const char*)A1;
    const char* a2c = (const char*)A2;
    const char* wcc = (const char*)Wcat;

    floatx4 acc[4][2];
    #pragma unroll
    for (int a = 0; a < 4; ++a)
        #pragma unroll
        for (int b = 0; b < 2; ++b) acc[a][b] = (floatx4){0.f, 0.f, 0.f, 0.f};

#define STAGE(kc, buf) do {                                                      \
        const char* asrc = ((kc) < 4) ? a1c : a2c;                               \
        int kb = ((kc) & 3) * 64;                                               \
        GLOAD16(asrc + (size_t)ra * 256 + kb + ua * 16, &sm[buf][w * 1024]);     \
        int kw = (kc) * 64;                                                     \
        GLOAD16(wcc + (size_t)col0 * 512 + kw + u0 * 16, &sm[buf][4096 + (w*2)*1024]);     \
        GLOAD16(wcc + (size_t)col1 * 512 + kw + u1 * 16, &sm[buf][4096 + (w*2+1)*1024]);   \
    } while (0)

    STAGE(0, 0);
    __syncthreads();                       // chunk 0 resident
    #pragma unroll
    for (int kc = 0; kc < 8; ++kc) {
        int buf = kc & 1;
        if (kc < 7) STAGE(kc + 1, buf ^ 1);   // async, in flight under compute
        const char* As = (const char*)&sm[buf][0];
        const char* Ws = (const char*)&sm[buf][4096];
        short8 afr[4], bfr[2];
        #pragma unroll
        for (int nb = 0; nb < 4; ++nb)
            afr[nb] = *(const short8*)(As + (nb * 16 + m) * 64 + qo);
        #pragma unroll
        for (int cb = 0; cb < 2; ++cb)
            bfr[cb] = *(const short8*)(Ws + (w * 32 + cb * 16 + m) * 64 + qo);
        #pragma unroll
        for (int nb = 0; nb < 4; ++nb)
            #pragma unroll
            for (int cb = 0; cb < 2; ++cb)
                acc[nb][cb] = __builtin_amdgcn_mfma_f32_16x16x32_bf16(afr[nb], bfr[cb], acc[nb][cb], 0, 0, 0);
        if (kc < 7) __syncthreads();       // drain in-flight loads + protect buf
    }
#undef STAGE

    #pragma unroll
    for (int cb = 0; cb < 2; ++cb) {
        int col = w * 32 + cb * 16 + m;
        float bv = bias[col];
        #pragma unroll
        for (int nb = 0; nb < 4; ++nb) {
            #pragma unroll
            for (int rr = 0; rr < 4; ++rr) {
                int row = nodeBase + nb * 16 + quad * 4 + rr;
                if (row < N_NODES) {
                    float v = acc[nb][cb][rr] + bv;
                    v = v > 0.f ? v : 0.f;
                    out[(size_t)row * 128 + col] = f2bf(v);
                    if (f8out) f8out[(size_t)row * 128 + col] = fp8b(v);
                }
            }
        }
    }
}

// ---- global_add_pool + LayerNorm + linear head (vectorized loads) ----
__global__ __launch_bounds__(256)
void pool_ln_out_kernel(const unsigned short* __restrict__ h2,
                        const int* __restrict__ batch,
                        const float* __restrict__ ln_g, const float* __restrict__ ln_b,
                        const float* __restrict__ Wlin, const float* __restrict__ blin,
                        float* __restrict__ out) {
    int g = blockIdx.x;
    int t = threadIdx.x;   // 256 threads
    int lane = t & 63, w = t >> 6;
    __shared__ int se[2];
    if (t < 2) {
        int target = g + t;
        int lo = 0, hi = N_NODES;
        while (lo < hi) {
            int mid = (lo + hi) >> 1;
            if (batch[mid] < target) lo = mid + 1; else hi = mid;
        }
        se[t] = lo;
    }
    __syncthreads();
    int s = se[0], e = se[1];
    int ns = t >> 4;       // 0..15 node stripe
    int chg = t & 15;      // channel group (8 ch)
    f32x2 a[4];
    a[0] = a[1] = a[2] = a[3] = (f32x2){0.f, 0.f};
    for (int n = s + ns; n < e; n += 16) {
        uint4 v = *(const uint4*)(h2 + (size_t)n * 128 + chg * 8);
        acc4(a, v);
    }
    #pragma unroll
    for (int i = 0; i < 4; ++i) {
        a[i].x += __shfl_xor(a[i].x, 16, 64);
        a[i].y += __shfl_xor(a[i].y, 16, 64);
        a[i].x += __shfl_xor(a[i].x, 32, 64);
        a[i].y += __shfl_xor(a[i].y, 32, 64);
    }
    __shared__ float sw[4][128];
    if (lane < 16) {
        #pragma unroll
        for (int k = 0; k < 4; ++k) {
            sw[w][chg * 8 + 2 * k]     = a[k].x;
            sw[w][chg * 8 + 2 * k + 1] = a[k].y;
        }
    }
    __syncthreads();
    __shared__ float red[128];
    float sum = 0.f;
    if (t < 128) {
        sum = sw[0][t] + sw[1][t] + sw[2][t] + sw[3][t];
        red[t] = sum;
    }
    __syncthreads();
    for (int off = 64; off > 0; off >>= 1) {
        if (t < off) red[t] += red[t + off];
        __syncthreads();
    }
    float mu = red[0] * (1.f / 128.f);
    __syncthreads();
    float dv = sum - mu;
    if (t < 128) red[t] = dv * dv;
    __syncthreads();
    for (int off = 64; off > 0; off >>= 1) {
        if (t < off) red[t] += red[t + off];
        __syncthreads();
    }
    float var = red[0] * (1.f / 128.f);
    __syncthreads();
    __shared__ float r0[128], r1[128];
    if (t < 128) {
        float gn = dv * rsqrtf(var + LN_EPS) * ln_g[t] + ln_b[t];
        r0[t] = gn * Wlin[t];
        r1[t] = gn * Wlin[128 + t];
    }
    __syncthreads();
    for (int off = 64; off > 0; off >>= 1) {
        if (t < off) { r0[t] += r0[t + off]; r1[t] += r1[t + off]; }
        __syncthreads();
    }
    if (t == 0) {
        out[g * 2 + 0] = r0[0] + blin[0];
        out[g * 2 + 1] = r1[0] + blin[1];
    }
}

extern "C" void kernel_launch(void* const* d_in, const int* in_sizes, int n_in,
                              void* d_out, int out_size, void* d_ws, size_t ws_size,
                              hipStream_t stream) {
    const float* x    = (const float*)d_in[0];
    const int*   ei   = (const int*)d_in[1];
    const int*   batch= (const int*)d_in[2];
    const float* W1l  = (const float*)d_in[3];
    const float* b1l  = (const float*)d_in[4];
    const float* W1r  = (const float*)d_in[5];
    const float* W2l  = (const float*)d_in[6];
    const float* b2l  = (const float*)d_in[7];
    const float* W2r  = (const float*)d_in[8];
    const float* ln_g = (const float*)d_in[9];
    const float* ln_b = (const float*)d_in[10];
    const float* Wlin = (const float*)d_in[11];
    const float* blin = (const float*)d_in[12];
    float* out = (float*)d_out;

    char* ws = (char*)d_ws;
    size_t off = 0;
    auto alloc = [&](size_t bytes) {
        char* p = ws + off;
        off = (off + bytes + 255) & ~(size_t)255;
        return p;
    };
    unsigned short* xbf  = (unsigned short*)alloc((size_t)N_NODES * D * 2); // later reused for h2
    unsigned short* aggb = (unsigned short*)alloc((size_t)N_NODES * D * 2); // aliased by binned
    unsigned short* h1   = (unsigned short*)alloc((size_t)N_NODES * D * 2);
    unsigned*       xf8  = (unsigned*)alloc((size_t)N_NODES * D + 128);     // fp8 x table (+dummy row); reused as h1f8
    unsigned short* Wc1  = (unsigned short*)alloc(128 * 256 * 2);
    unsigned short* Wc2  = (unsigned short*)alloc(128 * 256 * 2);
    int2* row_info   = (int2*)alloc((size_t)N_NODES * 8);
    int* src_sorted  = (int*)alloc(((size_t)NBUCKETS * CAP + 8192) * 4);    // +slack for unguarded preloads
    int* cursor      = (int*)alloc(NBUCKETS * 4);
    int* dhist       = (int*)alloc(128 * 4);    // dhist[64] + dcur[64]
    int* dcur        = dhist + 64;
    int* perm        = (int*)alloc((size_t)N_NODES * 4);
    unsigned* binned = (unsigned*)aggb;   // 7.6 MB <= 25.6 MB; consumed before aggb written
    unsigned char* h1f8 = (unsigned char*)xf8;  // xf8 dead after aggregate1 (dummy row stays zeroed)

    const int* srcI = ei;            // edge_index[0]
    const int* dstI = ei + N_EDGES;  // edge_index[1]

    prep_kernel<<<12500, 256, 0, stream>>>(x, xbf, xf8, W1l, W1r, W2l, W2r, Wc1, Wc2, cursor, dhist);
    bin_scatter_kernel<<<(N_EDGES + CHUNK - 1) / CHUNK, 256, 0, stream>>>(srcI, dstI, cursor, binned);
    bucket_build_kernel<<<NBUCKETS, 256, 0, stream>>>(binned, cursor, row_info, src_sorted, dhist);
    perm_kernel<<<NBUCKETS, 256, 0, stream>>>(row_info, dhist, dcur, perm);

    aggregate_kernel<<<6250, 256, 0, stream>>>((const unsigned char*)xf8, src_sorted, row_info, perm, aggb);
    gemm_kernel<<<1563, 256, 0, stream>>>(aggb, xbf, Wc1, b1l, h1, h1f8);
    aggregate_kernel<<<6250, 256, 0, stream>>>(h1f8, src_sorted, row_info, perm, aggb);
    gemm_kernel<<<1563, 256, 0, stream>>>(aggb, h1, Wc2, b2l, xbf, nullptr);
    pool_ln_out_kernel<<<NUM_GRAPHS, 256, 0, stream>>>(xbf, batch, ln_g, ln_b, Wlin, blin, out);
}

// Round 9
// 300.491 us; speedup vs baseline: 2.6872x; 2.6872x over previous
//
#include <hip/hip_runtime.h>
#include <hip/hip_bf16.h>
#include <hip/hip_fp8.h>

#define N_NODES   100000
#define N_EDGES   1600000
#define NUM_GRAPHS 1024
#define D         128
#define LN_EPS    1e-5f
#define NBUCKETS  391     // buckets of 256 nodes: bucket = dst >> 8
#define CAP       4864    // fixed bucket capacity (mean 4096 + 12 sigma); CAP/256 = 19
#define CHUNK     4096    // edges per bin_scatter block

typedef __attribute__((ext_vector_type(8))) short short8;
typedef __attribute__((ext_vector_type(4))) float floatx4;
typedef __attribute__((ext_vector_type(2))) float f32x2;

static __device__ __forceinline__ unsigned short f2bf(float f) {
    __hip_bfloat16 h = __float2bfloat16(f);
    return *reinterpret_cast<unsigned short*>(&h);
}
static __device__ __forceinline__ unsigned char fp8b(float v) {
    __hip_fp8_e4m3 t = (__hip_fp8_e4m3)v;
    return *reinterpret_cast<unsigned char*>(&t);
}
// accumulate 8 bf16 channels (one uint4) into 4 packed fp32 pairs
static __device__ __forceinline__ void acc4(f32x2* acc, uint4 v) {
    acc[0] += (f32x2){__uint_as_float(v.x << 16), __uint_as_float(v.x & 0xffff0000u)};
    acc[1] += (f32x2){__uint_as_float(v.y << 16), __uint_as_float(v.y & 0xffff0000u)};
    acc[2] += (f32x2){__uint_as_float(v.z << 16), __uint_as_float(v.z & 0xffff0000u)};
    acc[3] += (f32x2){__uint_as_float(v.w << 16), __uint_as_float(v.w & 0xffff0000u)};
}

// ---- fp8 e4m3 (OCP) pack/unpack ----
#if __has_builtin(__builtin_amdgcn_cvt_pk_f32_fp8)
#define UNPK_FP8(x, w) __builtin_amdgcn_cvt_pk_f32_fp8((x), (w))
#else
static __device__ __forceinline__ f32x2 unpk_fp8_sw(unsigned x, bool w) {
    unsigned s = w ? (x >> 16) : (x & 0xffffu);
    __hip_fp8_e4m3 a, b;
    *reinterpret_cast<unsigned char*>(&a) = (unsigned char)(s & 0xff);
    *reinterpret_cast<unsigned char*>(&b) = (unsigned char)((s >> 8) & 0xff);
    return (f32x2){(float)a, (float)b};
}
#define UNPK_FP8(x, w) unpk_fp8_sw((x), (w))
#endif

#if __has_builtin(__builtin_amdgcn_cvt_pk_fp8_f32)
#define PK_FP8(a, b, old, w) ((unsigned)__builtin_amdgcn_cvt_pk_fp8_f32((a), (b), (int)(old), (w)))
#else
static __device__ __forceinline__ unsigned pk_fp8_sw(float a, float b) {
    __hip_fp8_e4m3 fa = (__hip_fp8_e4m3)a;
    __hip_fp8_e4m3 fb = (__hip_fp8_e4m3)b;
    return (unsigned)*reinterpret_cast<unsigned char*>(&fa) |
           ((unsigned)*reinterpret_cast<unsigned char*>(&fb) << 8);
}
#define PK_FP8(a, b, old, w) ((w) ? ((((unsigned)(old)) & 0xffffu) | (pk_fp8_sw((a),(b)) << 16)) \
                                  : ((((unsigned)(old)) & 0xffff0000u) | pk_fp8_sw((a),(b))))
#endif

// async 16B global->LDS; lds ptr must be wave-uniform base (HW adds lane*16)
#define GLOAD16(g, l) __builtin_amdgcn_global_load_lds( \
    (const __attribute__((address_space(1))) void*)(g), \
    (__attribute__((address_space(3))) void*)(l), 16, 0, 0)

// ---- fused prep: x -> bf16 + fp8 tables, weight concat+cvt, cursor init ----
__global__ __launch_bounds__(256)
void prep_kernel(const float* __restrict__ x, unsigned short* __restrict__ xbf,
                 unsigned* __restrict__ xf8,
                 const float* __restrict__ W1l, const float* __restrict__ W1r,
                 const float* __restrict__ W2l, const float* __restrict__ W2r,
                 unsigned short* __restrict__ Wc1, unsigned short* __restrict__ Wc2,
                 int* __restrict__ cursor, int* __restrict__ dhist) {
    int i = blockIdx.x * 256 + threadIdx.x;     // float4 index, 3.2M exact
    float4 v = reinterpret_cast<const float4*>(x)[i];
    ushort4 o;
    o.x = f2bf(v.x); o.y = f2bf(v.y); o.z = f2bf(v.z); o.w = f2bf(v.w);
    reinterpret_cast<ushort4*>(xbf)[i] = o;
    unsigned p = PK_FP8(v.x, v.y, 0u, false);
    p = PK_FP8(v.z, v.w, p, true);
    xf8[i] = p;                                 // 4 fp8 bytes, coalesced
    if (blockIdx.x < 256) {                     // 65536 weight elements
        int layer = i >> 15;
        int rem = i & 32767;
        int c = rem >> 8;
        int k = rem & 255;
        const float* Wl = layer ? W2l : W1l;
        const float* Wr = layer ? W2r : W1r;
        unsigned short* dst = layer ? Wc2 : Wc1;
        float wv = (k < 128) ? Wl[c * 128 + k] : Wr[c * 128 + (k - 128)];
        dst[c * 256 + k] = f2bf(wv);
    }
    if (blockIdx.x == 256) {
        for (int b = threadIdx.x; b < NBUCKETS; b += 256)
            cursor[b] = b * CAP;
        // zero dummy row N_NODES of the fp8 table (degree padding target)
        if (threadIdx.x < 32)
            xf8[(size_t)N_NODES * 32 + threadIdx.x] = 0u;
        if (threadIdx.x < 128)                  // dhist[64] + dcur[64]
            dhist[threadIdx.x] = 0;
    }
}

// ---- scatter edges into fixed-capacity dst buckets; 4B packed records ----
// rec = (dst&255)<<17 | src   (src < 2^17)
__global__ __launch_bounds__(256)
void bin_scatter_kernel(const int* __restrict__ src, const int* __restrict__ dst,
                        int* __restrict__ cursor, unsigned* __restrict__ binned) {
    __shared__ int cnt[NBUCKETS];
    __shared__ int base[NBUCKETS];
    int chunkBase = blockIdx.x * CHUNK;
    for (int i = threadIdx.x; i < NBUCKETS; i += 256) cnt[i] = 0;
    __syncthreads();
    int es[16], ed[16], lofs[16];
    #pragma unroll
    for (int j = 0; j < 16; ++j) {
        int e = chunkBase + j * 256 + threadIdx.x;
        if (e < N_EDGES) {
            es[j] = src[e];
            ed[j] = dst[e];
            lofs[j] = atomicAdd(&cnt[ed[j] >> 8], 1);
        }
    }
    __syncthreads();
    for (int i = threadIdx.x; i < NBUCKETS; i += 256) {
        int c = cnt[i];
        base[i] = c ? atomicAdd(&cursor[i], c) : 0;
    }
    __syncthreads();
    #pragma unroll
    for (int j = 0; j < 16; ++j) {
        int e = chunkBase + j * 256 + threadIdx.x;
        if (e < N_EDGES) {
            int b = ed[j] >> 8;
            int pos = base[b] + lofs[j];
            if (pos < (b + 1) * CAP)            // capacity guard (never hit at 12 sigma)
                binned[pos] = ((unsigned)(ed[j] & 255) << 17) | (unsigned)es[j];
        }
    }
}

// One block per bucket (256 nodes), single pass: records + ranks in registers.
// Degree histogram via per-block LDS reduction -> <=64 global atomics/block
// (Guideline 12 -- the R8 global-atomic version was a 268us contention stall).
__global__ __launch_bounds__(256)
void bucket_build_kernel(const unsigned* __restrict__ binned, const int* __restrict__ cursor,
                         int2* __restrict__ row_info, int* __restrict__ src_sorted,
                         int* __restrict__ dhist) {
    __shared__ int scnt[256];
    __shared__ int sscan[256];
    __shared__ int lhist[64];
    int b = blockIdx.x;
    int t = threadIdx.x;
    int lo = b * CAP;
    int hi = cursor[b];
    int cap_end = lo + CAP;
    if (hi > cap_end) hi = cap_end;
    scnt[t] = 0;
    if (t < 64) lhist[t] = 0;
    __syncthreads();
    unsigned rec[19];
    short rnk[19];
    #pragma unroll
    for (int i = 0; i < 19; ++i) {
        int e = lo + t + i * 256;
        if (e < hi) {
            unsigned r = binned[e];
            rec[i] = r;
            rnk[i] = (short)atomicAdd(&scnt[r >> 17], 1);
        }
    }
    __syncthreads();
    int v = scnt[t];
    sscan[t] = v;
    __syncthreads();
    for (int off = 1; off < 256; off <<= 1) {
        int a = (t >= off) ? sscan[t - off] : 0;
        __syncthreads();
        sscan[t] += a;
        __syncthreads();
    }
    int ex = sscan[t] - v;
    int node = b * 256 + t;
    if (node < N_NODES) {
        row_info[node] = make_int2(lo + ex, v);
        atomicAdd(&lhist[v < 63 ? v : 63], 1);      // LDS atomic
    }
    scnt[t] = ex;
    __syncthreads();
    if (t < 64 && lhist[t])
        atomicAdd(&dhist[t], lhist[t]);             // one global atomic per bin
    #pragma unroll
    for (int i = 0; i < 19; ++i) {
        int e = lo + t + i * 256;
        if (e < hi) {
            unsigned r = rec[i];
            src_sorted[lo + scnt[r >> 17] + rnk[i]] = (int)(r & 0x1FFFFu);
        }
    }
}

// ---- degree counting-sort scatter (two-level; Guideline 12) ----
// Per-block LDS rank + one range-reservation atomic per (block, bin);
// pos = global-bin-prefix + block-base + local-rank. Bijective.
__global__ __launch_bounds__(256)
void perm_kernel(const int2* __restrict__ row_info, const int* __restrict__ dhist,
                 int* __restrict__ dcur, int* __restrict__ perm) {
    __shared__ int sc[64];
    __shared__ int lcnt[64];
    __shared__ int gbase[64];
    int t = threadIdx.x;
    if (t < 64) { sc[t] = dhist[t]; lcnt[t] = 0; }
    __syncthreads();
    for (int off = 1; off < 64; off <<= 1) {
        int a = (t < 64 && t >= off) ? sc[t - off] : 0;
        __syncthreads();
        if (t < 64) sc[t] += a;
        __syncthreads();
    }
    int node = blockIdx.x * 256 + t;
    int bin = 0, lrank = 0;
    if (node < N_NODES) {
        int dg = row_info[node].y;
        bin = dg < 63 ? dg : 63;
        lrank = atomicAdd(&lcnt[bin], 1);           // LDS atomic
    }
    __syncthreads();
    if (t < 64 && lcnt[t])
        gbase[t] = atomicAdd(&dcur[t], lcnt[t]);    // one global atomic per bin
    __syncthreads();
    if (node < N_NODES) {
        int base = bin ? sc[bin - 1] : 0;
        perm[base + gbase[bin] + lrank] = node;
    }
}

// ---- mean aggregation from fp8 table ----
// 4 nodes per wave via degree-sorted perm (co-scheduled nodes have ~equal
// degree -> dmax padding ~0). 16-lane group per node, lane owns 8 channels.
// Out-of-degree rounds cndmask-redirect to the zeroed dummy row N_NODES ->
// no masks, no tails, no cross-lane reduction, no LDS.
__global__ __launch_bounds__(256)
void aggregate_kernel(const unsigned char* __restrict__ feat8,
                      const int* __restrict__ src_sorted,
                      const int2* __restrict__ row_info,
                      const int* __restrict__ perm,
                      unsigned short* __restrict__ aggout) {
    int tid  = threadIdx.x;
    int wave = tid >> 6;
    int lane = tid & 63;
    int l16  = lane & 15;                       // channel octet within row
    int grpbase = lane & 48;                    // (lane>>4)*16
    int node = perm[blockIdx.x * 16 + wave * 4 + (lane >> 4)];  // 6250*16 = 100000
    int2 ri = row_info[node];
    int s = ri.x, deg = ri.y;
    // wave-uniform max degree across the 4 groups (near-equal after sort)
    int dmax = deg;
    dmax = max(dmax, __shfl_xor(dmax, 16, 64));
    dmax = max(dmax, __shfl_xor(dmax, 32, 64));
    unsigned chb = (unsigned)l16 * 8;           // byte offset within 128B row
    f32x2 a0[4], a1[4];
    #pragma unroll
    for (int i = 0; i < 4; ++i) { a0[i] = (f32x2){0.f, 0.f}; a1[i] = (f32x2){0.f, 0.f}; }

    for (int c0 = 0; c0 < dmax; c0 += 16) {
        int si = src_sorted[s + c0 + l16];      // group's edges c0..c0+15 (may read slack)
        int rel = deg - c0;                     // per-lane valid-round bound
        int rend = dmax - c0; if (rend > 16) rend = 16;
        int r = 0;
        for (; r + 2 <= rend; r += 2) {
            int u0 = __shfl(si, grpbase + r, 64);
            int u1 = __shfl(si, grpbase + r + 1, 64);
            u0 = (r < rel) ? u0 : N_NODES;
            u1 = (r + 1 < rel) ? u1 : N_NODES;
            uint2 v0 = *(const uint2*)(feat8 + (((unsigned)u0 << 7) + chb));
            uint2 v1 = *(const uint2*)(feat8 + (((unsigned)u1 << 7) + chb));
            a0[0] += UNPK_FP8(v0.x, false);
            a0[1] += UNPK_FP8(v0.x, true);
            a0[2] += UNPK_FP8(v0.y, false);
            a0[3] += UNPK_FP8(v0.y, true);
            a1[0] += UNPK_FP8(v1.x, false);
            a1[1] += UNPK_FP8(v1.x, true);
            a1[2] += UNPK_FP8(v1.y, false);
            a1[3] += UNPK_FP8(v1.y, true);
        }
        if (r < rend) {
            int u0 = __shfl(si, grpbase + r, 64);
            u0 = (r < rel) ? u0 : N_NODES;
            uint2 v0 = *(const uint2*)(feat8 + (((unsigned)u0 << 7) + chb));
            a0[0] += UNPK_FP8(v0.x, false);
            a0[1] += UNPK_FP8(v0.x, true);
            a0[2] += UNPK_FP8(v0.y, false);
            a0[3] += UNPK_FP8(v0.y, true);
        }
    }
    float inv = 1.f / (float)(deg > 1 ? deg : 1);
    f32x2 t0 = (a0[0] + a1[0]) * inv;
    f32x2 t1 = (a0[1] + a1[1]) * inv;
    f32x2 t2 = (a0[2] + a1[2]) * inv;
    f32x2 t3 = (a0[3] + a1[3]) * inv;
    uint4 o;
    o.x = (unsigned)f2bf(t0.x) | ((unsigned)f2bf(t0.y) << 16);
    o.y = (unsigned)f2bf(t1.x) | ((unsigned)f2bf(t1.y) << 16);
    o.z = (unsigned)f2bf(t2.x) | ((unsigned)f2bf(t2.y) << 16);
    o.w = (unsigned)f2bf(t3.x) | ((unsigned)f2bf(t3.y) << 16);
    *(uint4*)(aggout + (size_t)node * 128 + l16 * 8) = o;
}

// ---- fused SAGE linear: relu([A1|A2]@Wcat^T+b), bf16 MFMA ----
// T3 minimum-2-phase, 64-node tile (R6-verified). Optional fused fp8 output
// (layer 1) replaces the separate cvt pass. Swizzle per rule #21.
__global__ __launch_bounds__(256)
void gemm_kernel(const unsigned short* __restrict__ A1,   // k 0..127   (agg)
                 const unsigned short* __restrict__ A2,   // k 128..255 (self)
                 const unsigned short* __restrict__ Wcat, // [128 cols][256 k] bf16
                 const float* __restrict__ bias,
                 unsigned short* __restrict__ out,
                 unsigned char* __restrict__ f8out) {
    __shared__ unsigned char sm[2][12288];    // [buf][A 4KB | W 8KB]
    int tid  = threadIdx.x;
    int w    = tid >> 6;
    int lane = tid & 63;
    int quad = lane >> 4, m = lane & 15;
    int nodeBase = blockIdx.x * 64;
    int gm = (m & 3) ^ ((m >> 2) & 3);        // per-thread read-swizzle constant
    int qo = ((quad ^ gm) & 3) * 16;          // swizzled 16B-unit byte offset

    int arow = w * 16 + (lane >> 2);
    int ga   = (arow & 3) ^ ((arow >> 2) & 3);
    int ua   = (lane & 3) ^ ga;
    int ra   = nodeBase + arow; if (ra > N_NODES - 1) ra = N_NODES - 1;
    int col0 = w * 32 + (lane >> 2);
    int col1 = col0 + 16;
    int u0 = (lane & 3) ^ ((col0 & 3) ^ ((col0 >> 2) & 3));
    int u1 = (lane & 3) ^ ((col1 & 3) ^ ((col1 >> 2) & 3));
    const char* a1c = (const char*)A1;
    const char* a2c = (const char*)A2;
    const char* wcc = (const char*)Wcat;

    floatx4 acc[4][2];
    #pragma unroll
    for (int a = 0; a < 4; ++a)
        #pragma unroll
        for (int b = 0; b < 2; ++b) acc[a][b] = (floatx4){0.f, 0.f, 0.f, 0.f};

#define STAGE(kc, buf) do {                                                      \
        const char* asrc = ((kc) < 4) ? a1c : a2c;                               \
        int kb = ((kc) & 3) * 64;                                               \
        GLOAD16(asrc + (size_t)ra * 256 + kb + ua * 16, &sm[buf][w * 1024]);     \
        int kw = (kc) * 64;                                                     \
        GLOAD16(wcc + (size_t)col0 * 512 + kw + u0 * 16, &sm[buf][4096 + (w*2)*1024]);     \
        GLOAD16(wcc + (size_t)col1 * 512 + kw + u1 * 16, &sm[buf][4096 + (w*2+1)*1024]);   \
    } while (0)

    STAGE(0, 0);
    __syncthreads();                       // chunk 0 resident
    #pragma unroll
    for (int kc = 0; kc < 8; ++kc) {
        int buf = kc & 1;
        if (kc < 7) STAGE(kc + 1, buf ^ 1);   // async, in flight under compute
        const char* As = (const char*)&sm[buf][0];
        const char* Ws = (const char*)&sm[buf][4096];
        short8 afr[4], bfr[2];
        #pragma unroll
        for (int nb = 0; nb < 4; ++nb)
            afr[nb] = *(const short8*)(As + (nb * 16 + m) * 64 + qo);
        #pragma unroll
        for (int cb = 0; cb < 2; ++cb)
            bfr[cb] = *(const short8*)(Ws + (w * 32 + cb * 16 + m) * 64 + qo);
        #pragma unroll
        for (int nb = 0; nb < 4; ++nb)
            #pragma unroll
            for (int cb = 0; cb < 2; ++cb)
                acc[nb][cb] = __builtin_amdgcn_mfma_f32_16x16x32_bf16(afr[nb], bfr[cb], acc[nb][cb], 0, 0, 0);
        if (kc < 7) __syncthreads();       // drain in-flight loads + protect buf
    }
#undef STAGE

    #pragma unroll
    for (int cb = 0; cb < 2; ++cb) {
        int col = w * 32 + cb * 16 + m;
        float bv = bias[col];
        #pragma unroll
        for (int nb = 0; nb < 4; ++nb) {
            #pragma unroll
            for (int rr = 0; rr < 4; ++rr) {
                int row = nodeBase + nb * 16 + quad * 4 + rr;
                if (row < N_NODES) {
                    float v = acc[nb][cb][rr] + bv;
                    v = v > 0.f ? v : 0.f;
                    out[(size_t)row * 128 + col] = f2bf(v);
                    if (f8out) f8out[(size_t)row * 128 + col] = fp8b(v);
                }
            }
        }
    }
}

// ---- global_add_pool + LayerNorm + linear head (vectorized loads) ----
__global__ __launch_bounds__(256)
void pool_ln_out_kernel(const unsigned short* __restrict__ h2,
                        const int* __restrict__ batch,
                        const float* __restrict__ ln_g, const float* __restrict__ ln_b,
                        const float* __restrict__ Wlin, const float* __restrict__ blin,
                        float* __restrict__ out) {
    int g = blockIdx.x;
    int t = threadIdx.x;   // 256 threads
    int lane = t & 63, w = t >> 6;
    __shared__ int se[2];
    if (t < 2) {
        int target = g + t;
        int lo = 0, hi = N_NODES;
        while (lo < hi) {
            int mid = (lo + hi) >> 1;
            if (batch[mid] < target) lo = mid + 1; else hi = mid;
        }
        se[t] = lo;
    }
    __syncthreads();
    int s = se[0], e = se[1];
    int ns = t >> 4;       // 0..15 node stripe
    int chg = t & 15;      // channel group (8 ch)
    f32x2 a[4];
    a[0] = a[1] = a[2] = a[3] = (f32x2){0.f, 0.f};
    for (int n = s + ns; n < e; n += 16) {
        uint4 v = *(const uint4*)(h2 + (size_t)n * 128 + chg * 8);
        acc4(a, v);
    }
    #pragma unroll
    for (int i = 0; i < 4; ++i) {
        a[i].x += __shfl_xor(a[i].x, 16, 64);
        a[i].y += __shfl_xor(a[i].y, 16, 64);
        a[i].x += __shfl_xor(a[i].x, 32, 64);
        a[i].y += __shfl_xor(a[i].y, 32, 64);
    }
    __shared__ float sw[4][128];
    if (lane < 16) {
        #pragma unroll
        for (int k = 0; k < 4; ++k) {
            sw[w][chg * 8 + 2 * k]     = a[k].x;
            sw[w][chg * 8 + 2 * k + 1] = a[k].y;
        }
    }
    __syncthreads();
    __shared__ float red[128];
    float sum = 0.f;
    if (t < 128) {
        sum = sw[0][t] + sw[1][t] + sw[2][t] + sw[3][t];
        red[t] = sum;
    }
    __syncthreads();
    for (int off = 64; off > 0; off >>= 1) {
        if (t < off) red[t] += red[t + off];
        __syncthreads();
    }
    float mu = red[0] * (1.f / 128.f);
    __syncthreads();
    float dv = sum - mu;
    if (t < 128) red[t] = dv * dv;
    __syncthreads();
    for (int off = 64; off > 0; off >>= 1) {
        if (t < off) red[t] += red[t + off];
        __syncthreads();
    }
    float var = red[0] * (1.f / 128.f);
    __syncthreads();
    __shared__ float r0[128], r1[128];
    if (t < 128) {
        float gn = dv * rsqrtf(var + LN_EPS) * ln_g[t] + ln_b[t];
        r0[t] = gn * Wlin[t];
        r1[t] = gn * Wlin[128 + t];
    }
    __syncthreads();
    for (int off = 64; off > 0; off >>= 1) {
        if (t < off) { r0[t] += r0[t + off]; r1[t] += r1[t + off]; }
        __syncthreads();
    }
    if (t == 0) {
        out[g * 2 + 0] = r0[0] + blin[0];
        out[g * 2 + 1] = r1[0] + blin[1];
    }
}

extern "C" void kernel_launch(void* const* d_in, const int* in_sizes, int n_in,
                              void* d_out, int out_size, void* d_ws, size_t ws_size,
                              hipStream_t stream) {
    const float* x    = (const float*)d_in[0];
    const int*   ei   = (const int*)d_in[1];
    const int*   batch= (const int*)d_in[2];
    const float* W1l  = (const float*)d_in[3];
    const float* b1l  = (const float*)d_in[4];
    const float* W1r  = (const float*)d_in[5];
    const float* W2l  = (const float*)d_in[6];
    const float* b2l  = (const float*)d_in[7];
    const float* W2r  = (const float*)d_in[8];
    const float* ln_g = (const float*)d_in[9];
    const float* ln_b = (const float*)d_in[10];
    const float* Wlin = (const float*)d_in[11];
    const float* blin = (const float*)d_in[12];
    float* out = (float*)d_out;

    char* ws = (char*)d_ws;
    size_t off = 0;
    auto alloc = [&](size_t bytes) {
        char* p = ws + off;
        off = (off + bytes + 255) & ~(size_t)255;
        return p;
    };
    unsigned short* xbf  = (unsigned short*)alloc((size_t)N_NODES * D * 2); // later reused for h2
    unsigned short* aggb = (unsigned short*)alloc((size_t)N_NODES * D * 2); // aliased by binned
    unsigned short* h1   = (unsigned short*)alloc((size_t)N_NODES * D * 2);
    unsigned*       xf8  = (unsigned*)alloc((size_t)N_NODES * D + 128);     // fp8 x table (+dummy row); reused as h1f8
    unsigned short* Wc1  = (unsigned short*)alloc(128 * 256 * 2);
    unsigned short* Wc2  = (unsigned short*)alloc(128 * 256 * 2);
    int2* row_info   = (int2*)alloc((size_t)N_NODES * 8);
    int* src_sorted  = (int*)alloc(((size_t)NBUCKETS * CAP + 8192) * 4);    // +slack for unguarded preloads
    int* cursor      = (int*)alloc(NBUCKETS * 4);
    int* dhist       = (int*)alloc(128 * 4);    // dhist[64] + dcur[64]
    int* dcur        = dhist + 64;
    int* perm        = (int*)alloc((size_t)N_NODES * 4);
    unsigned* binned = (unsigned*)aggb;   // 7.6 MB <= 25.6 MB; consumed before aggb written
    unsigned char* h1f8 = (unsigned char*)xf8;  // xf8 dead after aggregate1 (dummy row stays zeroed)

    const int* srcI = ei;            // edge_index[0]
    const int* dstI = ei + N_EDGES;  // edge_index[1]

    prep_kernel<<<12500, 256, 0, stream>>>(x, xbf, xf8, W1l, W1r, W2l, W2r, Wc1, Wc2, cursor, dhist);
    bin_scatter_kernel<<<(N_EDGES + CHUNK - 1) / CHUNK, 256, 0, stream>>>(srcI, dstI, cursor, binned);
    bucket_build_kernel<<<NBUCKETS, 256, 0, stream>>>(binned, cursor, row_info, src_sorted, dhist);
    perm_kernel<<<NBUCKETS, 256, 0, stream>>>(row_info, dhist, dcur, perm);

    aggregate_kernel<<<6250, 256, 0, stream>>>((const unsigned char*)xf8, src_sorted, row_info, perm, aggb);
    gemm_kernel<<<1563, 256, 0, stream>>>(aggb, xbf, Wc1, b1l, h1, h1f8);
    aggregate_kernel<<<6250, 256, 0, stream>>>(h1f8, src_sorted, row_info, perm, aggb);
    gemm_kernel<<<1563, 256, 0, stream>>>(aggb, h1, Wc2, b2l, xbf, nullptr);
    pool_ln_out_kernel<<<NUM_GRAPHS, 256, 0, stream>>>(xbf, batch, ln_g, ln_b, Wlin, blin, out);
}

// Round 10
// 287.104 us; speedup vs baseline: 2.8125x; 1.0466x over previous
//
#include <hip/hip_runtime.h>
#include <hip/hip_bf16.h>
#include <hip/hip_fp8.h>

#define N_NODES   100000
#define N_EDGES   1600000
#define NUM_GRAPHS 1024
#define D         128
#define LN_EPS    1e-5f
#define NBUCKETS  391     // buckets of 256 nodes: bucket = dst >> 8
#define CAP       4864    // fixed bucket capacity (mean 4096 + 12 sigma); CAP/256 = 19
#define CHUNK     4096    // edges per bin_scatter block

typedef __attribute__((ext_vector_type(8))) short short8;
typedef __attribute__((ext_vector_type(4))) float floatx4;
typedef __attribute__((ext_vector_type(2))) float f32x2;

static __device__ __forceinline__ unsigned short f2bf(float f) {
    __hip_bfloat16 h = __float2bfloat16(f);
    return *reinterpret_cast<unsigned short*>(&h);
}
// accumulate 8 bf16 channels (one uint4) into 4 packed fp32 pairs
static __device__ __forceinline__ void acc4(f32x2* acc, uint4 v) {
    acc[0] += (f32x2){__uint_as_float(v.x << 16), __uint_as_float(v.x & 0xffff0000u)};
    acc[1] += (f32x2){__uint_as_float(v.y << 16), __uint_as_float(v.y & 0xffff0000u)};
    acc[2] += (f32x2){__uint_as_float(v.z << 16), __uint_as_float(v.z & 0xffff0000u)};
    acc[3] += (f32x2){__uint_as_float(v.w << 16), __uint_as_float(v.w & 0xffff0000u)};
}

// ---- fp8 e4m3 (OCP) pack/unpack ----
#if __has_builtin(__builtin_amdgcn_cvt_pk_f32_fp8)
#define UNPK_FP8(x, w) __builtin_amdgcn_cvt_pk_f32_fp8((x), (w))
#else
static __device__ __forceinline__ f32x2 unpk_fp8_sw(unsigned x, bool w) {
    unsigned s = w ? (x >> 16) : (x & 0xffffu);
    __hip_fp8_e4m3 a, b;
    *reinterpret_cast<unsigned char*>(&a) = (unsigned char)(s & 0xff);
    *reinterpret_cast<unsigned char*>(&b) = (unsigned char)((s >> 8) & 0xff);
    return (f32x2){(float)a, (float)b};
}
#define UNPK_FP8(x, w) unpk_fp8_sw((x), (w))
#endif

#if __has_builtin(__builtin_amdgcn_cvt_pk_fp8_f32)
#define PK_FP8(a, b, old, w) ((unsigned)__builtin_amdgcn_cvt_pk_fp8_f32((a), (b), (int)(old), (w)))
#else
static __device__ __forceinline__ unsigned pk_fp8_sw(float a, float b) {
    __hip_fp8_e4m3 fa = (__hip_fp8_e4m3)a;
    __hip_fp8_e4m3 fb = (__hip_fp8_e4m3)b;
    return (unsigned)*reinterpret_cast<unsigned char*>(&fa) |
           ((unsigned)*reinterpret_cast<unsigned char*>(&fb) << 8);
}
#define PK_FP8(a, b, old, w) ((w) ? ((((unsigned)(old)) & 0xffffu) | (pk_fp8_sw((a),(b)) << 16)) \
                                  : ((((unsigned)(old)) & 0xffff0000u) | pk_fp8_sw((a),(b))))
#endif

// async 16B global->LDS; lds ptr must be wave-uniform base (HW adds lane*16)
#define GLOAD16(g, l) __builtin_amdgcn_global_load_lds( \
    (const __attribute__((address_space(1))) void*)(g), \
    (__attribute__((address_space(3))) void*)(l), 16, 0, 0)

// ---- fused prep: x -> bf16 + fp8 tables, weight concat+cvt, cursor init ----
__global__ __launch_bounds__(256)
void prep_kernel(const float* __restrict__ x, unsigned short* __restrict__ xbf,
                 unsigned* __restrict__ xf8,
                 const float* __restrict__ W1l, const float* __restrict__ W1r,
                 const float* __restrict__ W2l, const float* __restrict__ W2r,
                 unsigned short* __restrict__ Wc1, unsigned short* __restrict__ Wc2,
                 int* __restrict__ cursor) {
    int i = blockIdx.x * 256 + threadIdx.x;     // float4 index, 3.2M exact
    float4 v = reinterpret_cast<const float4*>(x)[i];
    ushort4 o;
    o.x = f2bf(v.x); o.y = f2bf(v.y); o.z = f2bf(v.z); o.w = f2bf(v.w);
    reinterpret_cast<ushort4*>(xbf)[i] = o;
    unsigned p = PK_FP8(v.x, v.y, 0u, false);
    p = PK_FP8(v.z, v.w, p, true);
    xf8[i] = p;                                 // 4 fp8 bytes, coalesced
    if (blockIdx.x < 256) {                     // 65536 weight elements
        int layer = i >> 15;
        int rem = i & 32767;
        int c = rem >> 8;
        int k = rem & 255;
        const float* Wl = layer ? W2l : W1l;
        const float* Wr = layer ? W2r : W1r;
        unsigned short* dst = layer ? Wc2 : Wc1;
        float wv = (k < 128) ? Wl[c * 128 + k] : Wr[c * 128 + (k - 128)];
        dst[c * 256 + k] = f2bf(wv);
    }
    if (blockIdx.x == 256) {
        for (int b = threadIdx.x; b < NBUCKETS; b += 256)
            cursor[b] = b * CAP;
        // zero dummy row N_NODES of the fp8 table (degree padding target)
        if (threadIdx.x < 32)
            xf8[(size_t)N_NODES * 32 + threadIdx.x] = 0u;
    }
}

// ---- h1 bf16 -> fp8 table (coalesced, 8 ch per thread) ----
__global__ __launch_bounds__(256)
void cvt_h1_kernel(const unsigned short* __restrict__ h1, uint2* __restrict__ h1f8) {
    int i = blockIdx.x * 256 + threadIdx.x;     // 8-ch group, 1.6M exact
    uint4 v = reinterpret_cast<const uint4*>(h1)[i];
    float c0 = __uint_as_float(v.x << 16), c1 = __uint_as_float(v.x & 0xffff0000u);
    float c2 = __uint_as_float(v.y << 16), c3 = __uint_as_float(v.y & 0xffff0000u);
    float c4 = __uint_as_float(v.z << 16), c5 = __uint_as_float(v.z & 0xffff0000u);
    float c6 = __uint_as_float(v.w << 16), c7 = __uint_as_float(v.w & 0xffff0000u);
    unsigned lo = PK_FP8(c0, c1, 0u, false);
    lo = PK_FP8(c2, c3, lo, true);
    unsigned hi = PK_FP8(c4, c5, 0u, false);
    hi = PK_FP8(c6, c7, hi, true);
    h1f8[i] = make_uint2(lo, hi);
}

// ---- scatter edges into fixed-capacity dst buckets; 4B packed records ----
// rec = (dst&255)<<17 | src   (src < 2^17)
__global__ __launch_bounds__(256)
void bin_scatter_kernel(const int* __restrict__ src, const int* __restrict__ dst,
                        int* __restrict__ cursor, unsigned* __restrict__ binned) {
    __shared__ int cnt[NBUCKETS];
    __shared__ int base[NBUCKETS];
    int chunkBase = blockIdx.x * CHUNK;
    for (int i = threadIdx.x; i < NBUCKETS; i += 256) cnt[i] = 0;
    __syncthreads();
    int es[16], ed[16], lofs[16];
    #pragma unroll
    for (int j = 0; j < 16; ++j) {
        int e = chunkBase + j * 256 + threadIdx.x;
        if (e < N_EDGES) {
            es[j] = src[e];
            ed[j] = dst[e];
            lofs[j] = atomicAdd(&cnt[ed[j] >> 8], 1);
        }
    }
    __syncthreads();
    for (int i = threadIdx.x; i < NBUCKETS; i += 256) {
        int c = cnt[i];
        base[i] = c ? atomicAdd(&cursor[i], c) : 0;
    }
    __syncthreads();
    #pragma unroll
    for (int j = 0; j < 16; ++j) {
        int e = chunkBase + j * 256 + threadIdx.x;
        if (e < N_EDGES) {
            int b = ed[j] >> 8;
            int pos = base[b] + lofs[j];
            if (pos < (b + 1) * CAP)            // capacity guard (never hit at 12 sigma)
                binned[pos] = ((unsigned)(ed[j] & 255) << 17) | (unsigned)es[j];
        }
    }
}

// One block per bucket (256 nodes), single pass: records + ranks in registers.
// Adds an in-bucket degree counting-sort (LDS only, no global atomics):
// perm[b*256 + rank] = node, rank by degree within the bucket. Keeps perm
// bucket-contiguous (dense: buckets 0..389 full, bucket 390 has 160) so the
// aggregate XCD swizzle's L2 bucket-locality is preserved (R9 lesson).
__global__ __launch_bounds__(256)
void bucket_build_kernel(const unsigned* __restrict__ binned, const int* __restrict__ cursor,
                         int2* __restrict__ row_info, int* __restrict__ src_sorted,
                         int* __restrict__ perm) {
    __shared__ int scnt[256];
    __shared__ int sscan[256];
    __shared__ int dh[64];
    __shared__ int db[64];
    int b = blockIdx.x;
    int t = threadIdx.x;
    int lo = b * CAP;
    int hi = cursor[b];
    int cap_end = lo + CAP;
    if (hi > cap_end) hi = cap_end;
    scnt[t] = 0;
    if (t < 64) dh[t] = 0;
    __syncthreads();
    unsigned rec[19];
    short rnk[19];
    #pragma unroll
    for (int i = 0; i < 19; ++i) {
        int e = lo + t + i * 256;
        if (e < hi) {
            unsigned r = binned[e];
            rec[i] = r;
            rnk[i] = (short)atomicAdd(&scnt[r >> 17], 1);
        }
    }
    __syncthreads();
    int v = scnt[t];
    sscan[t] = v;
    __syncthreads();
    for (int off = 1; off < 256; off <<= 1) {
        int a = (t >= off) ? sscan[t - off] : 0;
        __syncthreads();
        sscan[t] += a;
        __syncthreads();
    }
    int ex = sscan[t] - v;
    int node = b * 256 + t;
    int bin = 0, lr = 0;
    bool valid = node < N_NODES;
    if (valid) {
        row_info[node] = make_int2(lo + ex, v);
        bin = v < 63 ? v : 63;
        lr = atomicAdd(&dh[bin], 1);            // LDS: count AND rank-in-bin
    }
    scnt[t] = ex;
    __syncthreads();
    if (t < 64) db[t] = dh[t];
    __syncthreads();
    for (int off = 1; off < 64; off <<= 1) {    // inclusive scan over 64 bins
        int a = (t < 64 && t >= off) ? db[t - off] : 0;
        __syncthreads();
        if (t < 64) db[t] += a;
        __syncthreads();
    }
    if (valid)
        perm[b * 256 + (db[bin] - dh[bin]) + lr] = node;   // excl. prefix + rank
    #pragma unroll
    for (int i = 0; i < 19; ++i) {
        int e = lo + t + i * 256;
        if (e < hi) {
            unsigned r = rec[i];
            src_sorted[lo + scnt[r >> 17] + rnk[i]] = (int)(r & 0x1FFFFu);
        }
    }
}

// ---- mean aggregation from fp8 table ----
// 4 nodes per wave via in-bucket degree-sorted perm (co-scheduled nodes have
// ~equal degree -> dmax padding ~0; perm stays bucket-local so the T1 XCD
// swizzle keeps each bucket's src working set on one XCD's L2).
// 16-lane group per node, lane owns 8 channels. Out-of-degree rounds
// cndmask-redirect to the zeroed dummy row N_NODES -> no masks, no tails,
// no cross-lane reduction, no LDS.
__global__ __launch_bounds__(256)
void aggregate_kernel(const unsigned char* __restrict__ feat8,
                      const int* __restrict__ src_sorted,
                      const int2* __restrict__ row_info,
                      const int* __restrict__ perm,
                      unsigned short* __restrict__ aggout) {
    int bid = blockIdx.x;
    int xcd = bid & 7;
    int idx = bid >> 3;
    int lb  = (xcd < 2) ? xcd * 782 + idx : 1564 + (xcd - 2) * 781 + idx;
    int tid  = threadIdx.x;
    int wave = tid >> 6;
    int lane = tid & 63;
    int l16  = lane & 15;                       // channel octet within row
    int grpbase = lane & 48;                    // (lane>>4)*16
    int node = perm[lb * 16 + wave * 4 + (lane >> 4)];     // 6250*16 = 100000
    int2 ri = row_info[node];
    int s = ri.x, deg = ri.y;
    // wave-uniform max degree across the 4 groups (near-equal after sort)
    int dmax = deg;
    dmax = max(dmax, __shfl_xor(dmax, 16, 64));
    dmax = max(dmax, __shfl_xor(dmax, 32, 64));
    unsigned chb = (unsigned)l16 * 8;           // byte offset within 128B row
    f32x2 a0[4], a1[4];
    #pragma unroll
    for (int i = 0; i < 4; ++i) { a0[i] = (f32x2){0.f, 0.f}; a1[i] = (f32x2){0.f, 0.f}; }

    for (int c0 = 0; c0 < dmax; c0 += 16) {
        int si = src_sorted[s + c0 + l16];      // group's edges c0..c0+15 (may read slack)
        int rel = deg - c0;                     // per-lane valid-round bound
        int rend = dmax - c0; if (rend > 16) rend = 16;
        int r = 0;
        for (; r + 2 <= rend; r += 2) {
            int u0 = __shfl(si, grpbase + r, 64);
            int u1 = __shfl(si, grpbase + r + 1, 64);
            u0 = (r < rel) ? u0 : N_NODES;
            u1 = (r + 1 < rel) ? u1 : N_NODES;
            uint2 v0 = *(const uint2*)(feat8 + (((unsigned)u0 << 7) + chb));
            uint2 v1 = *(const uint2*)(feat8 + (((unsigned)u1 << 7) + chb));
            a0[0] += UNPK_FP8(v0.x, false);
            a0[1] += UNPK_FP8(v0.x, true);
            a0[2] += UNPK_FP8(v0.y, false);
            a0[3] += UNPK_FP8(v0.y, true);
            a1[0] += UNPK_FP8(v1.x, false);
            a1[1] += UNPK_FP8(v1.x, true);
            a1[2] += UNPK_FP8(v1.y, false);
            a1[3] += UNPK_FP8(v1.y, true);
        }
        if (r < rend) {
            int u0 = __shfl(si, grpbase + r, 64);
            u0 = (r < rel) ? u0 : N_NODES;
            uint2 v0 = *(const uint2*)(feat8 + (((unsigned)u0 << 7) + chb));
            a0[0] += UNPK_FP8(v0.x, false);
            a0[1] += UNPK_FP8(v0.x, true);
            a0[2] += UNPK_FP8(v0.y, false);
            a0[3] += UNPK_FP8(v0.y, true);
        }
    }
    float inv = 1.f / (float)(deg > 1 ? deg : 1);
    f32x2 t0 = (a0[0] + a1[0]) * inv;
    f32x2 t1 = (a0[1] + a1[1]) * inv;
    f32x2 t2 = (a0[2] + a1[2]) * inv;
    f32x2 t3 = (a0[3] + a1[3]) * inv;
    uint4 o;
    o.x = (unsigned)f2bf(t0.x) | ((unsigned)f2bf(t0.y) << 16);
    o.y = (unsigned)f2bf(t1.x) | ((unsigned)f2bf(t1.y) << 16);
    o.z = (unsigned)f2bf(t2.x) | ((unsigned)f2bf(t2.y) << 16);
    o.w = (unsigned)f2bf(t3.x) | ((unsigned)f2bf(t3.y) << 16);
    *(uint4*)(aggout + (size_t)node * 128 + l16 * 8) = o;
}

// ---- fused SAGE linear: relu([A1|A2]@Wcat^T+b), bf16 MFMA ----
// T3 minimum-2-phase, 64-node tile (R6-verified). Swizzle per rule #21.
// NO fused fp8 output: stride-128 byte stores inflate WRITE 2.5x (R2, R9).
__global__ __launch_bounds__(256)
void gemm_kernel(const unsigned short* __restrict__ A1,   // k 0..127   (agg)
                 const unsigned short* __restrict__ A2,   // k 128..255 (self)
                 const unsigned short* __restrict__ Wcat, // [128 cols][256 k] bf16
                 const float* __restrict__ bias,
                 unsigned short* __restrict__ out) {
    __shared__ unsigned char sm[2][12288];    // [buf][A 4KB | W 8KB]
    int tid  = threadIdx.x;
    int w    = tid >> 6;
    int lane = tid & 63;
    int quad = lane >> 4, m = lane & 15;
    int nodeBase = blockIdx.x * 64;
    int gm = (m & 3) ^ ((m >> 2) & 3);        // per-thread read-swizzle constant
    int qo = ((quad ^ gm) & 3) * 16;          // swizzled 16B-unit byte offset

    int arow = w * 16 + (lane >> 2);
    int ga   = (arow & 3) ^ ((arow >> 2) & 3);
    int ua   = (lane & 3) ^ ga;
    int ra   = nodeBase + arow; if (ra > N_NODES - 1) ra = N_NODES - 1;
    int col0 = w * 32 + (lane >> 2);
    int col1 = col0 + 16;
    int u0 = (lane & 3) ^ ((col0 & 3) ^ ((col0 >> 2) & 3));
    int u1 = (lane & 3) ^ ((col1 & 3) ^ ((col1 >> 2) & 3));
    const char* a1c = (const char*)A1;
    const char* a2c = (const char*)A2;
    const char* wcc = (const char*)Wcat;

    floatx4 acc[4][2];
    #pragma unroll
    for (int a = 0; a < 4; ++a)
        #pragma unroll
        for (int b = 0; b < 2; ++b) acc[a][b] = (floatx4){0.f, 0.f, 0.f, 0.f};

#define STAGE(kc, buf) do {                                                      \
        const char* asrc = ((kc) < 4) ? a1c : a2c;                               \
        int kb = ((kc) & 3) * 64;                                               \
        GLOAD16(asrc + (size_t)ra * 256 + kb + ua * 16, &sm[buf][w * 1024]);     \
        int kw = (kc) * 64;                                                     \
        GLOAD16(wcc + (size_t)col0 * 512 + kw + u0 * 16, &sm[buf][4096 + (w*2)*1024]);     \
        GLOAD16(wcc + (size_t)col1 * 512 + kw + u1 * 16, &sm[buf][4096 + (w*2+1)*1024]);   \
    } while (0)

    STAGE(0, 0);
    __syncthreads();                       // chunk 0 resident
    #pragma unroll
    for (int kc = 0; kc < 8; ++kc) {
        int buf = kc & 1;
        if (kc < 7) STAGE(kc + 1, buf ^ 1);   // async, in flight under compute
        const char* As = (const char*)&sm[buf][0];
        const char* Ws = (const char*)&sm[buf][4096];
        short8 afr[4], bfr[2];
        #pragma unroll
        for (int nb = 0; nb < 4; ++nb)
            afr[nb] = *(const short8*)(As + (nb * 16 + m) * 64 + qo);
        #pragma unroll
        for (int cb = 0; cb < 2; ++cb)
            bfr[cb] = *(const short8*)(Ws + (w * 32 + cb * 16 + m) * 64 + qo);
        #pragma unroll
        for (int nb = 0; nb < 4; ++nb)
            #pragma unroll
            for (int cb = 0; cb < 2; ++cb)
                acc[nb][cb] = __builtin_amdgcn_mfma_f32_16x16x32_bf16(afr[nb], bfr[cb], acc[nb][cb], 0, 0, 0);
        if (kc < 7) __syncthreads();       // drain in-flight loads + protect buf
    }
#undef STAGE

    #pragma unroll
    for (int cb = 0; cb < 2; ++cb) {
        int col = w * 32 + cb * 16 + m;
        float bv = bias[col];
        #pragma unroll
        for (int nb = 0; nb < 4; ++nb) {
            #pragma unroll
            for (int rr = 0; rr < 4; ++rr) {
                int row = nodeBase + nb * 16 + quad * 4 + rr;
                if (row < N_NODES) {
                    float v = acc[nb][cb][rr] + bv;
                    v = v > 0.f ? v : 0.f;
                    out[(size_t)row * 128 + col] = f2bf(v);
                }
            }
        }
    }
}

// ---- global_add_pool + LayerNorm + linear head (vectorized loads) ----
__global__ __launch_bounds__(256)
void pool_ln_out_kernel(const unsigned short* __restrict__ h2,
                        const int* __restrict__ batch,
                        const float* __restrict__ ln_g, const float* __restrict__ ln_b,
                        const float* __restrict__ Wlin, const float* __restrict__ blin,
                        float* __restrict__ out) {
    int g = blockIdx.x;
    int t = threadIdx.x;   // 256 threads
    int lane = t & 63, w = t >> 6;
    __shared__ int se[2];
    if (t < 2) {
        int target = g + t;
        int lo = 0, hi = N_NODES;
        while (lo < hi) {
            int mid = (lo + hi) >> 1;
            if (batch[mid] < target) lo = mid + 1; else hi = mid;
        }
        se[t] = lo;
    }
    __syncthreads();
    int s = se[0], e = se[1];
    int ns = t >> 4;       // 0..15 node stripe
    int chg = t & 15;      // channel group (8 ch)
    f32x2 a[4];
    a[0] = a[1] = a[2] = a[3] = (f32x2){0.f, 0.f};
    for (int n = s + ns; n < e; n += 16) {
        uint4 v = *(const uint4*)(h2 + (size_t)n * 128 + chg * 8);
        acc4(a, v);
    }
    #pragma unroll
    for (int i = 0; i < 4; ++i) {
        a[i].x += __shfl_xor(a[i].x, 16, 64);
        a[i].y += __shfl_xor(a[i].y, 16, 64);
        a[i].x += __shfl_xor(a[i].x, 32, 64);
        a[i].y += __shfl_xor(a[i].y, 32, 64);
    }
    __shared__ float sw[4][128];
    if (lane < 16) {
        #pragma unroll
        for (int k = 0; k < 4; ++k) {
            sw[w][chg * 8 + 2 * k]     = a[k].x;
            sw[w][chg * 8 + 2 * k + 1] = a[k].y;
        }
    }
    __syncthreads();
    __shared__ float red[128];
    float sum = 0.f;
    if (t < 128) {
        sum = sw[0][t] + sw[1][t] + sw[2][t] + sw[3][t];
        red[t] = sum;
    }
    __syncthreads();
    for (int off = 64; off > 0; off >>= 1) {
        if (t < off) red[t] += red[t + off];
        __syncthreads();
    }
    float mu = red[0] * (1.f / 128.f);
    __syncthreads();
    float dv = sum - mu;
    if (t < 128) red[t] = dv * dv;
    __syncthreads();
    for (int off = 64; off > 0; off >>= 1) {
        if (t < off) red[t] += red[t + off];
        __syncthreads();
    }
    float var = red[0] * (1.f / 128.f);
    __syncthreads();
    __shared__ float r0[128], r1[128];
    if (t < 128) {
        float gn = dv * rsqrtf(var + LN_EPS) * ln_g[t] + ln_b[t];
        r0[t] = gn * Wlin[t];
        r1[t] = gn * Wlin[128 + t];
    }
    __syncthreads();
    for (int off = 64; off > 0; off >>= 1) {
        if (t < off) { r0[t] += r0[t + off]; r1[t] += r1[t + off]; }
        __syncthreads();
    }
    if (t == 0) {
        out[g * 2 + 0] = r0[0] + blin[0];
        out[g * 2 + 1] = r1[0] + blin[1];
    }
}

extern "C" void kernel_launch(void* const* d_in, const int* in_sizes, int n_in,
                              void* d_out, int out_size, void* d_ws, size_t ws_size,
                              hipStream_t stream) {
    const float* x    = (const float*)d_in[0];
    const int*   ei   = (const int*)d_in[1];
    const int*   batch= (const int*)d_in[2];
    const float* W1l  = (const float*)d_in[3];
    const float* b1l  = (const float*)d_in[4];
    const float* W1r  = (const float*)d_in[5];
    const float* W2l  = (const float*)d_in[6];
    const float* b2l  = (const float*)d_in[7];
    const float* W2r  = (const float*)d_in[8];
    const float* ln_g = (const float*)d_in[9];
    const float* ln_b = (const float*)d_in[10];
    const float* Wlin = (const float*)d_in[11];
    const float* blin = (const float*)d_in[12];
    float* out = (float*)d_out;

    char* ws = (char*)d_ws;
    size_t off = 0;
    auto alloc = [&](size_t bytes) {
        char* p = ws + off;
        off = (off + bytes + 255) & ~(size_t)255;
        return p;
    };
    unsigned short* xbf  = (unsigned short*)alloc((size_t)N_NODES * D * 2); // later reused for h2
    unsigned short* aggb = (unsigned short*)alloc((size_t)N_NODES * D * 2); // aliased by binned
    unsigned short* h1   = (unsigned short*)alloc((size_t)N_NODES * D * 2);
    unsigned*       xf8  = (unsigned*)alloc((size_t)N_NODES * D + 128);     // fp8 x table (+dummy row); reused as h1f8
    unsigned short* Wc1  = (unsigned short*)alloc(128 * 256 * 2);
    unsigned short* Wc2  = (unsigned short*)alloc(128 * 256 * 2);
    int2* row_info   = (int2*)alloc((size_t)N_NODES * 8);
    int* src_sorted  = (int*)alloc(((size_t)NBUCKETS * CAP + 8192) * 4);    // +slack for unguarded preloads
    int* cursor      = (int*)alloc(NBUCKETS * 4);
    int* perm        = (int*)alloc((size_t)N_NODES * 4);
    unsigned* binned = (unsigned*)aggb;   // 7.6 MB <= 25.6 MB; consumed before aggb written
    uint2* h1f8      = (uint2*)xf8;       // xf8 dead after aggregate1 (dummy row stays zeroed)

    const int* srcI = ei;            // edge_index[0]
    const int* dstI = ei + N_EDGES;  // edge_index[1]

    prep_kernel<<<12500, 256, 0, stream>>>(x, xbf, xf8, W1l, W1r, W2l, W2r, Wc1, Wc2, cursor);
    bin_scatter_kernel<<<(N_EDGES + CHUNK - 1) / CHUNK, 256, 0, stream>>>(srcI, dstI, cursor, binned);
    bucket_build_kernel<<<NBUCKETS, 256, 0, stream>>>(binned, cursor, row_info, src_sorted, perm);

    aggregate_kernel<<<6250, 256, 0, stream>>>((const unsigned char*)xf8, src_sorted, row_info, perm, aggb);
    gemm_kernel<<<1563, 256, 0, stream>>>(aggb, xbf, Wc1, b1l, h1);
    cvt_h1_kernel<<<6250, 256, 0, stream>>>(h1, h1f8);
    aggregate_kernel<<<6250, 256, 0, stream>>>((const unsigned char*)h1f8, src_sorted, row_info, perm, aggb);
    gemm_kernel<<<1563, 256, 0, stream>>>(aggb, h1, Wc2, b2l, xbf);
    pool_ln_out_kernel<<<NUM_GRAPHS, 256, 0, stream>>>(xbf, batch, ln_g, ln_b, Wlin, blin, out);
}

// Round 11
// 283.381 us; speedup vs baseline: 2.8495x; 1.0131x over previous
//
#include <hip/hip_runtime.h>
#include <hip/hip_bf16.h>
#include <hip/hip_fp8.h>

#define N_NODES   100000
#define N_EDGES   1600000
#define NUM_GRAPHS 1024
#define D         128
#define LN_EPS    1e-5f
#define NBUCKETS  391     // buckets of 256 nodes: bucket = dst >> 8
#define CAP       4864    // fixed bucket capacity (mean 4096 + 12 sigma); CAP/256 = 19
#define CHUNK     4096    // edges per bin_scatter block

typedef __attribute__((ext_vector_type(8))) short short8;
typedef __attribute__((ext_vector_type(4))) float floatx4;
typedef __attribute__((ext_vector_type(2))) float f32x2;

static __device__ __forceinline__ unsigned short f2bf(float f) {
    __hip_bfloat16 h = __float2bfloat16(f);
    return *reinterpret_cast<unsigned short*>(&h);
}
// accumulate 8 bf16 channels (one uint4) into 4 packed fp32 pairs
static __device__ __forceinline__ void acc4(f32x2* acc, uint4 v) {
    acc[0] += (f32x2){__uint_as_float(v.x << 16), __uint_as_float(v.x & 0xffff0000u)};
    acc[1] += (f32x2){__uint_as_float(v.y << 16), __uint_as_float(v.y & 0xffff0000u)};
    acc[2] += (f32x2){__uint_as_float(v.z << 16), __uint_as_float(v.z & 0xffff0000u)};
    acc[3] += (f32x2){__uint_as_float(v.w << 16), __uint_as_float(v.w & 0xffff0000u)};
}

// ---- fp8 e4m3 (OCP) pack/unpack ----
#if __has_builtin(__builtin_amdgcn_cvt_pk_f32_fp8)
#define UNPK_FP8(x, w) __builtin_amdgcn_cvt_pk_f32_fp8((x), (w))
#else
static __device__ __forceinline__ f32x2 unpk_fp8_sw(unsigned x, bool w) {
    unsigned s = w ? (x >> 16) : (x & 0xffffu);
    __hip_fp8_e4m3 a, b;
    *reinterpret_cast<unsigned char*>(&a) = (unsigned char)(s & 0xff);
    *reinterpret_cast<unsigned char*>(&b) = (unsigned char)((s >> 8) & 0xff);
    return (f32x2){(float)a, (float)b};
}
#define UNPK_FP8(x, w) unpk_fp8_sw((x), (w))
#endif

#if __has_builtin(__builtin_amdgcn_cvt_pk_fp8_f32)
#define PK_FP8(a, b, old, w) ((unsigned)__builtin_amdgcn_cvt_pk_fp8_f32((a), (b), (int)(old), (w)))
#else
static __device__ __forceinline__ unsigned pk_fp8_sw(float a, float b) {
    __hip_fp8_e4m3 fa = (__hip_fp8_e4m3)a;
    __hip_fp8_e4m3 fb = (__hip_fp8_e4m3)b;
    return (unsigned)*reinterpret_cast<unsigned char*>(&fa) |
           ((unsigned)*reinterpret_cast<unsigned char*>(&fb) << 8);
}
#define PK_FP8(a, b, old, w) ((w) ? ((((unsigned)(old)) & 0xffffu) | (pk_fp8_sw((a),(b)) << 16)) \
                                  : ((((unsigned)(old)) & 0xffff0000u) | pk_fp8_sw((a),(b))))
#endif

// async 16B global->LDS; lds ptr must be wave-uniform base (HW adds lane*16)
#define GLOAD16(g, l) __builtin_amdgcn_global_load_lds( \
    (const __attribute__((address_space(1))) void*)(g), \
    (__attribute__((address_space(3))) void*)(l), 16, 0, 0)

// ---- fused prep: x -> bf16 + fp8 tables, weight concat+cvt, cursor init ----
__global__ __launch_bounds__(256)
void prep_kernel(const float* __restrict__ x, unsigned short* __restrict__ xbf,
                 unsigned* __restrict__ xf8,
                 const float* __restrict__ W1l, const float* __restrict__ W1r,
                 const float* __restrict__ W2l, const float* __restrict__ W2r,
                 unsigned short* __restrict__ Wc1, unsigned short* __restrict__ Wc2,
                 int* __restrict__ cursor) {
    int i = blockIdx.x * 256 + threadIdx.x;     // float4 index, 3.2M exact
    float4 v = reinterpret_cast<const float4*>(x)[i];
    ushort4 o;
    o.x = f2bf(v.x); o.y = f2bf(v.y); o.z = f2bf(v.z); o.w = f2bf(v.w);
    reinterpret_cast<ushort4*>(xbf)[i] = o;
    unsigned p = PK_FP8(v.x, v.y, 0u, false);
    p = PK_FP8(v.z, v.w, p, true);
    xf8[i] = p;                                 // 4 fp8 bytes, coalesced
    if (blockIdx.x < 256) {                     // 65536 weight elements
        int layer = i >> 15;
        int rem = i & 32767;
        int c = rem >> 8;
        int k = rem & 255;
        const float* Wl = layer ? W2l : W1l;
        const float* Wr = layer ? W2r : W1r;
        unsigned short* dst = layer ? Wc2 : Wc1;
        float wv = (k < 128) ? Wl[c * 128 + k] : Wr[c * 128 + (k - 128)];
        dst[c * 256 + k] = f2bf(wv);
    }
    if (blockIdx.x == 256) {
        for (int b = threadIdx.x; b < NBUCKETS; b += 256)
            cursor[b] = b * CAP;
        // zero dummy row N_NODES of the fp8 table (degree padding target)
        if (threadIdx.x < 32)
            xf8[(size_t)N_NODES * 32 + threadIdx.x] = 0u;
    }
}

// ---- h1 bf16 -> fp8 table (coalesced, 8 ch per thread) ----
__global__ __launch_bounds__(256)
void cvt_h1_kernel(const unsigned short* __restrict__ h1, uint2* __restrict__ h1f8) {
    int i = blockIdx.x * 256 + threadIdx.x;     // 8-ch group, 1.6M exact
    uint4 v = reinterpret_cast<const uint4*>(h1)[i];
    float c0 = __uint_as_float(v.x << 16), c1 = __uint_as_float(v.x & 0xffff0000u);
    float c2 = __uint_as_float(v.y << 16), c3 = __uint_as_float(v.y & 0xffff0000u);
    float c4 = __uint_as_float(v.z << 16), c5 = __uint_as_float(v.z & 0xffff0000u);
    float c6 = __uint_as_float(v.w << 16), c7 = __uint_as_float(v.w & 0xffff0000u);
    unsigned lo = PK_FP8(c0, c1, 0u, false);
    lo = PK_FP8(c2, c3, lo, true);
    unsigned hi = PK_FP8(c4, c5, 0u, false);
    hi = PK_FP8(c6, c7, hi, true);
    h1f8[i] = make_uint2(lo, hi);
}

// ---- scatter edges into fixed-capacity dst buckets; 4B packed records ----
// rec = (dst&255)<<17 | src   (src < 2^17)
__global__ __launch_bounds__(256)
void bin_scatter_kernel(const int* __restrict__ src, const int* __restrict__ dst,
                        int* __restrict__ cursor, unsigned* __restrict__ binned) {
    __shared__ int cnt[NBUCKETS];
    __shared__ int base[NBUCKETS];
    int chunkBase = blockIdx.x * CHUNK;
    for (int i = threadIdx.x; i < NBUCKETS; i += 256) cnt[i] = 0;
    __syncthreads();
    int es[16], ed[16], lofs[16];
    #pragma unroll
    for (int j = 0; j < 16; ++j) {
        int e = chunkBase + j * 256 + threadIdx.x;
        if (e < N_EDGES) {
            es[j] = src[e];
            ed[j] = dst[e];
            lofs[j] = atomicAdd(&cnt[ed[j] >> 8], 1);
        }
    }
    __syncthreads();
    for (int i = threadIdx.x; i < NBUCKETS; i += 256) {
        int c = cnt[i];
        base[i] = c ? atomicAdd(&cursor[i], c) : 0;
    }
    __syncthreads();
    #pragma unroll
    for (int j = 0; j < 16; ++j) {
        int e = chunkBase + j * 256 + threadIdx.x;
        if (e < N_EDGES) {
            int b = ed[j] >> 8;
            int pos = base[b] + lofs[j];
            if (pos < (b + 1) * CAP)            // capacity guard (never hit at 12 sigma)
                binned[pos] = ((unsigned)(ed[j] & 255) << 17) | (unsigned)es[j];
        }
    }
}

// One block per bucket (256 nodes), single pass: records + ranks in registers.
// Adds an in-bucket degree counting-sort (LDS only, no global atomics):
// perm[b*256 + rank] = node, rank by degree within the bucket. Keeps perm
// bucket-contiguous so the aggregate XCD swizzle's L2 bucket-locality is
// preserved (R9 lesson: global sort destroyed it).
__global__ __launch_bounds__(256)
void bucket_build_kernel(const unsigned* __restrict__ binned, const int* __restrict__ cursor,
                         int2* __restrict__ row_info, int* __restrict__ src_sorted,
                         int* __restrict__ perm) {
    __shared__ int scnt[256];
    __shared__ int sscan[256];
    __shared__ int dh[64];
    __shared__ int db[64];
    int b = blockIdx.x;
    int t = threadIdx.x;
    int lo = b * CAP;
    int hi = cursor[b];
    int cap_end = lo + CAP;
    if (hi > cap_end) hi = cap_end;
    scnt[t] = 0;
    if (t < 64) dh[t] = 0;
    __syncthreads();
    unsigned rec[19];
    short rnk[19];
    #pragma unroll
    for (int i = 0; i < 19; ++i) {
        int e = lo + t + i * 256;
        if (e < hi) {
            unsigned r = binned[e];
            rec[i] = r;
            rnk[i] = (short)atomicAdd(&scnt[r >> 17], 1);
        }
    }
    __syncthreads();
    int v = scnt[t];
    sscan[t] = v;
    __syncthreads();
    for (int off = 1; off < 256; off <<= 1) {
        int a = (t >= off) ? sscan[t - off] : 0;
        __syncthreads();
        sscan[t] += a;
        __syncthreads();
    }
    int ex = sscan[t] - v;
    int node = b * 256 + t;
    int bin = 0, lr = 0;
    bool valid = node < N_NODES;
    if (valid) {
        row_info[node] = make_int2(lo + ex, v);
        bin = v < 63 ? v : 63;
        lr = atomicAdd(&dh[bin], 1);            // LDS: count AND rank-in-bin
    }
    scnt[t] = ex;
    __syncthreads();
    if (t < 64) db[t] = dh[t];
    __syncthreads();
    for (int off = 1; off < 64; off <<= 1) {    // inclusive scan over 64 bins
        int a = (t < 64 && t >= off) ? db[t - off] : 0;
        __syncthreads();
        if (t < 64) db[t] += a;
        __syncthreads();
    }
    if (valid)
        perm[b * 256 + (db[bin] - dh[bin]) + lr] = node;   // excl. prefix + rank
    #pragma unroll
    for (int i = 0; i < 19; ++i) {
        int e = lo + t + i * 256;
        if (e < hi) {
            unsigned r = rec[i];
            src_sorted[lo + scnt[r >> 17] + rnk[i]] = (int)(r & 0x1FFFFu);
        }
    }
}

// ---- mean aggregation from fp8 table ----
// 4 nodes per wave via in-bucket degree-sorted perm (co-scheduled nodes have
// ~equal degree -> dmax padding ~0; perm stays bucket-local so the T1 XCD
// swizzle keeps each bucket's src working set on one XCD's L2).
// 16-lane group per node, lane owns 8 channels. Out-of-degree rounds
// cndmask-redirect to the zeroed dummy row N_NODES -> no masks, no tails,
// no cross-lane reduction, no LDS. 4-deep gather unroll (R11): 4 independent
// uint2 loads in flight per round + next index-vector prefetched under the
// current rounds -> exposed L2/L3 latency per edge halved vs 2-deep.
__global__ __launch_bounds__(256)
void aggregate_kernel(const unsigned char* __restrict__ feat8,
                      const int* __restrict__ src_sorted,
                      const int2* __restrict__ row_info,
                      const int* __restrict__ perm,
                      unsigned short* __restrict__ aggout) {
    int bid = blockIdx.x;
    int xcd = bid & 7;
    int idx = bid >> 3;
    int lb  = (xcd < 2) ? xcd * 782 + idx : 1564 + (xcd - 2) * 781 + idx;
    int tid  = threadIdx.x;
    int wave = tid >> 6;
    int lane = tid & 63;
    int l16  = lane & 15;                       // channel octet within row
    int grpbase = lane & 48;                    // (lane>>4)*16
    int node = perm[lb * 16 + wave * 4 + (lane >> 4)];     // 6250*16 = 100000
    int2 ri = row_info[node];
    int s = ri.x, deg = ri.y;
    // wave-uniform max degree across the 4 groups (near-equal after sort)
    int dmax = deg;
    dmax = max(dmax, __shfl_xor(dmax, 16, 64));
    dmax = max(dmax, __shfl_xor(dmax, 32, 64));
    unsigned chb = (unsigned)l16 * 8;           // byte offset within 128B row
    f32x2 a0[4], a1[4], a2[4], a3[4];
    #pragma unroll
    for (int i = 0; i < 4; ++i) {
        a0[i] = (f32x2){0.f, 0.f}; a1[i] = (f32x2){0.f, 0.f};
        a2[i] = (f32x2){0.f, 0.f}; a3[i] = (f32x2){0.f, 0.f};
    }

    int si = src_sorted[s + l16];               // first 16 edges (slack-padded)
    for (int c0 = 0; c0 < dmax; c0 += 16) {
        int si_next = si;
        if (c0 + 16 < dmax)                     // wave-uniform; rides under rounds
            si_next = src_sorted[s + c0 + 16 + l16];
        int rel = deg - c0;                     // per-lane valid-round bound
        int rend = dmax - c0; if (rend > 16) rend = 16;
        int r = 0;
        for (; r + 4 <= rend; r += 4) {         // 4 independent gathers in flight
            int u0 = __shfl(si, grpbase + r, 64);
            int u1 = __shfl(si, grpbase + r + 1, 64);
            int u2 = __shfl(si, grpbase + r + 2, 64);
            int u3 = __shfl(si, grpbase + r + 3, 64);
            u0 = (r < rel) ? u0 : N_NODES;
            u1 = (r + 1 < rel) ? u1 : N_NODES;
            u2 = (r + 2 < rel) ? u2 : N_NODES;
            u3 = (r + 3 < rel) ? u3 : N_NODES;
            uint2 v0 = *(const uint2*)(feat8 + (((unsigned)u0 << 7) + chb));
            uint2 v1 = *(const uint2*)(feat8 + (((unsigned)u1 << 7) + chb));
            uint2 v2 = *(const uint2*)(feat8 + (((unsigned)u2 << 7) + chb));
            uint2 v3 = *(const uint2*)(feat8 + (((unsigned)u3 << 7) + chb));
            a0[0] += UNPK_FP8(v0.x, false);
            a0[1] += UNPK_FP8(v0.x, true);
            a0[2] += UNPK_FP8(v0.y, false);
            a0[3] += UNPK_FP8(v0.y, true);
            a1[0] += UNPK_FP8(v1.x, false);
            a1[1] += UNPK_FP8(v1.x, true);
            a1[2] += UNPK_FP8(v1.y, false);
            a1[3] += UNPK_FP8(v1.y, true);
            a2[0] += UNPK_FP8(v2.x, false);
            a2[1] += UNPK_FP8(v2.x, true);
            a2[2] += UNPK_FP8(v2.y, false);
            a2[3] += UNPK_FP8(v2.y, true);
            a3[0] += UNPK_FP8(v3.x, false);
            a3[1] += UNPK_FP8(v3.x, true);
            a3[2] += UNPK_FP8(v3.y, false);
            a3[3] += UNPK_FP8(v3.y, true);
        }
        for (; r + 2 <= rend; r += 2) {
            int u0 = __shfl(si, grpbase + r, 64);
            int u1 = __shfl(si, grpbase + r + 1, 64);
            u0 = (r < rel) ? u0 : N_NODES;
            u1 = (r + 1 < rel) ? u1 : N_NODES;
            uint2 v0 = *(const uint2*)(feat8 + (((unsigned)u0 << 7) + chb));
            uint2 v1 = *(const uint2*)(feat8 + (((unsigned)u1 << 7) + chb));
            a0[0] += UNPK_FP8(v0.x, false);
            a0[1] += UNPK_FP8(v0.x, true);
            a0[2] += UNPK_FP8(v0.y, false);
            a0[3] += UNPK_FP8(v0.y, true);
            a1[0] += UNPK_FP8(v1.x, false);
            a1[1] += UNPK_FP8(v1.x, true);
            a1[2] += UNPK_FP8(v1.y, false);
            a1[3] += UNPK_FP8(v1.y, true);
        }
        if (r < rend) {
            int u0 = __shfl(si, grpbase + r, 64);
            u0 = (r < rel) ? u0 : N_NODES;
            uint2 v0 = *(const uint2*)(feat8 + (((unsigned)u0 << 7) + chb));
            a0[0] += UNPK_FP8(v0.x, false);
            a0[1] += UNPK_FP8(v0.x, true);
            a0[2] += UNPK_FP8(v0.y, false);
            a0[3] += UNPK_FP8(v0.y, true);
        }
        si = si_next;
    }
    float inv = 1.f / (float)(deg > 1 ? deg : 1);
    f32x2 t0 = ((a0[0] + a1[0]) + (a2[0] + a3[0])) * inv;
    f32x2 t1 = ((a0[1] + a1[1]) + (a2[1] + a3[1])) * inv;
    f32x2 t2 = ((a0[2] + a1[2]) + (a2[2] + a3[2])) * inv;
    f32x2 t3 = ((a0[3] + a1[3]) + (a2[3] + a3[3])) * inv;
    uint4 o;
    o.x = (unsigned)f2bf(t0.x) | ((unsigned)f2bf(t0.y) << 16);
    o.y = (unsigned)f2bf(t1.x) | ((unsigned)f2bf(t1.y) << 16);
    o.z = (unsigned)f2bf(t2.x) | ((unsigned)f2bf(t2.y) << 16);
    o.w = (unsigned)f2bf(t3.x) | ((unsigned)f2bf(t3.y) << 16);
    *(uint4*)(aggout + (size_t)node * 128 + l16 * 8) = o;
}

// ---- fused SAGE linear: relu([A1|A2]@Wcat^T+b), bf16 MFMA ----
// T3 minimum-2-phase, 64-node tile (R6-verified). Swizzle per rule #21.
// NO fused fp8 output: stride-128 byte stores inflate WRITE 2.5x (R2, R9).
__global__ __launch_bounds__(256)
void gemm_kernel(const unsigned short* __restrict__ A1,   // k 0..127   (agg)
                 const unsigned short* __restrict__ A2,   // k 128..255 (self)
                 const unsigned short* __restrict__ Wcat, // [128 cols][256 k] bf16
                 const float* __restrict__ bias,
                 unsigned short* __restrict__ out) {
    __shared__ unsigned char sm[2][12288];    // [buf][A 4KB | W 8KB]
    int tid  = threadIdx.x;
    int w    = tid >> 6;
    int lane = tid & 63;
    int quad = lane >> 4, m = lane & 15;
    int nodeBase = blockIdx.x * 64;
    int gm = (m & 3) ^ ((m >> 2) & 3);        // per-thread read-swizzle constant
    int qo = ((quad ^ gm) & 3) * 16;          // swizzled 16B-unit byte offset

    int arow = w * 16 + (lane >> 2);
    int ga   = (arow & 3) ^ ((arow >> 2) & 3);
    int ua   = (lane & 3) ^ ga;
    int ra   = nodeBase + arow; if (ra > N_NODES - 1) ra = N_NODES - 1;
    int col0 = w * 32 + (lane >> 2);
    int col1 = col0 + 16;
    int u0 = (lane & 3) ^ ((col0 & 3) ^ ((col0 >> 2) & 3));
    int u1 = (lane & 3) ^ ((col1 & 3) ^ ((col1 >> 2) & 3));
    const char* a1c = (const char*)A1;
    const char* a2c = (const char*)A2;
    const char* wcc = (const char*)Wcat;

    floatx4 acc[4][2];
    #pragma unroll
    for (int a = 0; a < 4; ++a)
        #pragma unroll
        for (int b = 0; b < 2; ++b) acc[a][b] = (floatx4){0.f, 0.f, 0.f, 0.f};

#define STAGE(kc, buf) do {                                                      \
        const char* asrc = ((kc) < 4) ? a1c : a2c;                               \
        int kb = ((kc) & 3) * 64;                                               \
        GLOAD16(asrc + (size_t)ra * 256 + kb + ua * 16, &sm[buf][w * 1024]);     \
        int kw = (kc) * 64;                                                     \
        GLOAD16(wcc + (size_t)col0 * 512 + kw + u0 * 16, &sm[buf][4096 + (w*2)*1024]);     \
        GLOAD16(wcc + (size_t)col1 * 512 + kw + u1 * 16, &sm[buf][4096 + (w*2+1)*1024]);   \
    } while (0)

    STAGE(0, 0);
    __syncthreads();                       // chunk 0 resident
    #pragma unroll
    for (int kc = 0; kc < 8; ++kc) {
        int buf = kc & 1;
        if (kc < 7) STAGE(kc + 1, buf ^ 1);   // async, in flight under compute
        const char* As = (const char*)&sm[buf][0];
        const char* Ws = (const char*)&sm[buf][4096];
        short8 afr[4], bfr[2];
        #pragma unroll
        for (int nb = 0; nb < 4; ++nb)
            afr[nb] = *(const short8*)(As + (nb * 16 + m) * 64 + qo);
        #pragma unroll
        for (int cb = 0; cb < 2; ++cb)
            bfr[cb] = *(const short8*)(Ws + (w * 32 + cb * 16 + m) * 64 + qo);
        #pragma unroll
        for (int nb = 0; nb < 4; ++nb)
            #pragma unroll
            for (int cb = 0; cb < 2; ++cb)
                acc[nb][cb] = __builtin_amdgcn_mfma_f32_16x16x32_bf16(afr[nb], bfr[cb], acc[nb][cb], 0, 0, 0);
        if (kc < 7) __syncthreads();       // drain in-flight loads + protect buf
    }
#undef STAGE

    #pragma unroll
    for (int cb = 0; cb < 2; ++cb) {
        int col = w * 32 + cb * 16 + m;
        float bv = bias[col];
        #pragma unroll
        for (int nb = 0; nb < 4; ++nb) {
            #pragma unroll
            for (int rr = 0; rr < 4; ++rr) {
                int row = nodeBase + nb * 16 + quad * 4 + rr;
                if (row < N_NODES) {
                    float v = acc[nb][cb][rr] + bv;
                    v = v > 0.f ? v : 0.f;
                    out[(size_t)row * 128 + col] = f2bf(v);
                }
            }
        }
    }
}

// ---- global_add_pool + LayerNorm + linear head (vectorized loads) ----
__global__ __launch_bounds__(256)
void pool_ln_out_kernel(const unsigned short* __restrict__ h2,
                        const int* __restrict__ batch,
                        const float* __restrict__ ln_g, const float* __restrict__ ln_b,
                        const float* __restrict__ Wlin, const float* __restrict__ blin,
                        float* __restrict__ out) {
    int g = blockIdx.x;
    int t = threadIdx.x;   // 256 threads
    int lane = t & 63, w = t >> 6;
    __shared__ int se[2];
    if (t < 2) {
        int target = g + t;
        int lo = 0, hi = N_NODES;
        while (lo < hi) {
            int mid = (lo + hi) >> 1;
            if (batch[mid] < target) lo = mid + 1; else hi = mid;
        }
        se[t] = lo;
    }
    __syncthreads();
    int s = se[0], e = se[1];
    int ns = t >> 4;       // 0..15 node stripe
    int chg = t & 15;      // channel group (8 ch)
    f32x2 a[4];
    a[0] = a[1] = a[2] = a[3] = (f32x2){0.f, 0.f};
    for (int n = s + ns; n < e; n += 16) {
        uint4 v = *(const uint4*)(h2 + (size_t)n * 128 + chg * 8);
        acc4(a, v);
    }
    #pragma unroll
    for (int i = 0; i < 4; ++i) {
        a[i].x += __shfl_xor(a[i].x, 16, 64);
        a[i].y += __shfl_xor(a[i].y, 16, 64);
        a[i].x += __shfl_xor(a[i].x, 32, 64);
        a[i].y += __shfl_xor(a[i].y, 32, 64);
    }
    __shared__ float sw[4][128];
    if (lane < 16) {
        #pragma unroll
        for (int k = 0; k < 4; ++k) {
            sw[w][chg * 8 + 2 * k]     = a[k].x;
            sw[w][chg * 8 + 2 * k + 1] = a[k].y;
        }
    }
    __syncthreads();
    __shared__ float red[128];
    float sum = 0.f;
    if (t < 128) {
        sum = sw[0][t] + sw[1][t] + sw[2][t] + sw[3][t];
        red[t] = sum;
    }
    __syncthreads();
    for (int off = 64; off > 0; off >>= 1) {
        if (t < off) red[t] += red[t + off];
        __syncthreads();
    }
    float mu = red[0] * (1.f / 128.f);
    __syncthreads();
    float dv = sum - mu;
    if (t < 128) red[t] = dv * dv;
    __syncthreads();
    for (int off = 64; off > 0; off >>= 1) {
        if (t < off) red[t] += red[t + off];
        __syncthreads();
    }
    float var = red[0] * (1.f / 128.f);
    __syncthreads();
    __shared__ float r0[128], r1[128];
    if (t < 128) {
        float gn = dv * rsqrtf(var + LN_EPS) * ln_g[t] + ln_b[t];
        r0[t] = gn * Wlin[t];
        r1[t] = gn * Wlin[128 + t];
    }
    __syncthreads();
    for (int off = 64; off > 0; off >>= 1) {
        if (t < off) { r0[t] += r0[t + off]; r1[t] += r1[t + off]; }
        __syncthreads();
    }
    if (t == 0) {
        out[g * 2 + 0] = r0[0] + blin[0];
        out[g * 2 + 1] = r1[0] + blin[1];
    }
}

extern "C" void kernel_launch(void* const* d_in, const int* in_sizes, int n_in,
                              void* d_out, int out_size, void* d_ws, size_t ws_size,
                              hipStream_t stream) {
    const float* x    = (const float*)d_in[0];
    const int*   ei   = (const int*)d_in[1];
    const int*   batch= (const int*)d_in[2];
    const float* W1l  = (const float*)d_in[3];
    const float* b1l  = (const float*)d_in[4];
    const float* W1r  = (const float*)d_in[5];
    const float* W2l  = (const float*)d_in[6];
    const float* b2l  = (const float*)d_in[7];
    const float* W2r  = (const float*)d_in[8];
    const float* ln_g = (const float*)d_in[9];
    const float* ln_b = (const float*)d_in[10];
    const float* Wlin = (const float*)d_in[11];
    const float* blin = (const float*)d_in[12];
    float* out = (float*)d_out;

    char* ws = (char*)d_ws;
    size_t off = 0;
    auto alloc = [&](size_t bytes) {
        char* p = ws + off;
        off = (off + bytes + 255) & ~(size_t)255;
        return p;
    };
    unsigned short* xbf  = (unsigned short*)alloc((size_t)N_NODES * D * 2); // later reused for h2
    unsigned short* aggb = (unsigned short*)alloc((size_t)N_NODES * D * 2); // aliased by binned
    unsigned short* h1   = (unsigned short*)alloc((size_t)N_NODES * D * 2);
    unsigned*       xf8  = (unsigned*)alloc((size_t)N_NODES * D + 128);     // fp8 x table (+dummy row); reused as h1f8
    unsigned short* Wc1  = (unsigned short*)alloc(128 * 256 * 2);
    unsigned short* Wc2  = (unsigned short*)alloc(128 * 256 * 2);
    int2* row_info   = (int2*)alloc((size_t)N_NODES * 8);
    int* src_sorted  = (int*)alloc(((size_t)NBUCKETS * CAP + 8192) * 4);    // +slack for unguarded preloads
    int* cursor      = (int*)alloc(NBUCKETS * 4);
    int* perm        = (int*)alloc((size_t)N_NODES * 4);
    unsigned* binned = (unsigned*)aggb;   // 7.6 MB <= 25.6 MB; consumed before aggb written
    uint2* h1f8      = (uint2*)xf8;       // xf8 dead after aggregate1 (dummy row stays zeroed)

    const int* srcI = ei;            // edge_index[0]
    const int* dstI = ei + N_EDGES;  // edge_index[1]

    prep_kernel<<<12500, 256, 0, stream>>>(x, xbf, xf8, W1l, W1r, W2l, W2r, Wc1, Wc2, cursor);
    bin_scatter_kernel<<<(N_EDGES + CHUNK - 1) / CHUNK, 256, 0, stream>>>(srcI, dstI, cursor, binned);
    bucket_build_kernel<<<NBUCKETS, 256, 0, stream>>>(binned, cursor, row_info, src_sorted, perm);

    aggregate_kernel<<<6250, 256, 0, stream>>>((const unsigned char*)xf8, src_sorted, row_info, perm, aggb);
    gemm_kernel<<<1563, 256, 0, stream>>>(aggb, xbf, Wc1, b1l, h1);
    cvt_h1_kernel<<<6250, 256, 0, stream>>>(h1, h1f8);
    aggregate_kernel<<<6250, 256, 0, stream>>>((const unsigned char*)h1f8, src_sorted, row_info, perm, aggb);
    gemm_kernel<<<1563, 256, 0, stream>>>(aggb, h1, Wc2, b2l, xbf);
    pool_ln_out_kernel<<<NUM_GRAPHS, 256, 0, stream>>>(xbf, batch, ln_g, ln_b, Wlin, blin, out);
}

// Round 12
// 281.604 us; speedup vs baseline: 2.8674x; 1.0063x over previous
//
#include <hip/hip_runtime.h>
#include <hip/hip_bf16.h>
#include <hip/hip_fp8.h>

#define N_NODES   100000
#define N_EDGES   1600000
#define NUM_GRAPHS 1024
#define D         128
#define LN_EPS    1e-5f
#define NBUCKETS  391     // buckets of 256 nodes: bucket = dst >> 8
#define CAP       4864    // fixed bucket capacity (mean 4096 + 12 sigma); CAP/256 = 19
#define CHUNK     4096    // edges per bin_scatter block

typedef __attribute__((ext_vector_type(8))) short short8;
typedef __attribute__((ext_vector_type(4))) float floatx4;
typedef __attribute__((ext_vector_type(2))) float f32x2;

static __device__ __forceinline__ unsigned short f2bf(float f) {
    __hip_bfloat16 h = __float2bfloat16(f);
    return *reinterpret_cast<unsigned short*>(&h);
}
// accumulate 8 bf16 channels (one uint4) into 4 packed fp32 pairs
static __device__ __forceinline__ void acc4(f32x2* acc, uint4 v) {
    acc[0] += (f32x2){__uint_as_float(v.x << 16), __uint_as_float(v.x & 0xffff0000u)};
    acc[1] += (f32x2){__uint_as_float(v.y << 16), __uint_as_float(v.y & 0xffff0000u)};
    acc[2] += (f32x2){__uint_as_float(v.z << 16), __uint_as_float(v.z & 0xffff0000u)};
    acc[3] += (f32x2){__uint_as_float(v.w << 16), __uint_as_float(v.w & 0xffff0000u)};
}

// ---- fp8 e4m3 (OCP) pack/unpack ----
#if __has_builtin(__builtin_amdgcn_cvt_pk_f32_fp8)
#define UNPK_FP8(x, w) __builtin_amdgcn_cvt_pk_f32_fp8((x), (w))
#else
static __device__ __forceinline__ f32x2 unpk_fp8_sw(unsigned x, bool w) {
    unsigned s = w ? (x >> 16) : (x & 0xffffu);
    __hip_fp8_e4m3 a, b;
    *reinterpret_cast<unsigned char*>(&a) = (unsigned char)(s & 0xff);
    *reinterpret_cast<unsigned char*>(&b) = (unsigned char)((s >> 8) & 0xff);
    return (f32x2){(float)a, (float)b};
}
#define UNPK_FP8(x, w) unpk_fp8_sw((x), (w))
#endif

#if __has_builtin(__builtin_amdgcn_cvt_pk_fp8_f32)
#define PK_FP8(a, b, old, w) ((unsigned)__builtin_amdgcn_cvt_pk_fp8_f32((a), (b), (int)(old), (w)))
#else
static __device__ __forceinline__ unsigned pk_fp8_sw(float a, float b) {
    __hip_fp8_e4m3 fa = (__hip_fp8_e4m3)a;
    __hip_fp8_e4m3 fb = (__hip_fp8_e4m3)b;
    return (unsigned)*reinterpret_cast<unsigned char*>(&fa) |
           ((unsigned)*reinterpret_cast<unsigned char*>(&fb) << 8);
}
#define PK_FP8(a, b, old, w) ((w) ? ((((unsigned)(old)) & 0xffffu) | (pk_fp8_sw((a),(b)) << 16)) \
                                  : ((((unsigned)(old)) & 0xffff0000u) | pk_fp8_sw((a),(b))))
#endif

// async 16B global->LDS; lds ptr must be wave-uniform base (HW adds lane*16)
#define GLOAD16(g, l) __builtin_amdgcn_global_load_lds( \
    (const __attribute__((address_space(1))) void*)(g), \
    (__attribute__((address_space(3))) void*)(l), 16, 0, 0)

// ---- fused prep: x -> bf16 + fp8 tables, weight concat+cvt, cursor init ----
__global__ __launch_bounds__(256)
void prep_kernel(const float* __restrict__ x, unsigned short* __restrict__ xbf,
                 unsigned* __restrict__ xf8,
                 const float* __restrict__ W1l, const float* __restrict__ W1r,
                 const float* __restrict__ W2l, const float* __restrict__ W2r,
                 unsigned short* __restrict__ Wc1, unsigned short* __restrict__ Wc2,
                 int* __restrict__ cursor) {
    int i = blockIdx.x * 256 + threadIdx.x;     // float4 index, 3.2M exact
    float4 v = reinterpret_cast<const float4*>(x)[i];
    ushort4 o;
    o.x = f2bf(v.x); o.y = f2bf(v.y); o.z = f2bf(v.z); o.w = f2bf(v.w);
    reinterpret_cast<ushort4*>(xbf)[i] = o;
    unsigned p = PK_FP8(v.x, v.y, 0u, false);
    p = PK_FP8(v.z, v.w, p, true);
    xf8[i] = p;                                 // 4 fp8 bytes, coalesced
    if (blockIdx.x < 256) {                     // 65536 weight elements
        int layer = i >> 15;
        int rem = i & 32767;
        int c = rem >> 8;
        int k = rem & 255;
        const float* Wl = layer ? W2l : W1l;
        const float* Wr = layer ? W2r : W1r;
        unsigned short* dst = layer ? Wc2 : Wc1;
        float wv = (k < 128) ? Wl[c * 128 + k] : Wr[c * 128 + (k - 128)];
        dst[c * 256 + k] = f2bf(wv);
    }
    if (blockIdx.x == 256) {
        for (int b = threadIdx.x; b < NBUCKETS; b += 256)
            cursor[b] = b * CAP;
        // zero dummy row N_NODES of the fp8 table (degree padding target)
        if (threadIdx.x < 32)
            xf8[(size_t)N_NODES * 32 + threadIdx.x] = 0u;
    }
}

// ---- h1 bf16 -> fp8 table (coalesced, 8 ch per thread) ----
__global__ __launch_bounds__(256)
void cvt_h1_kernel(const unsigned short* __restrict__ h1, uint2* __restrict__ h1f8) {
    int i = blockIdx.x * 256 + threadIdx.x;     // 8-ch group, 1.6M exact
    uint4 v = reinterpret_cast<const uint4*>(h1)[i];
    float c0 = __uint_as_float(v.x << 16), c1 = __uint_as_float(v.x & 0xffff0000u);
    float c2 = __uint_as_float(v.y << 16), c3 = __uint_as_float(v.y & 0xffff0000u);
    float c4 = __uint_as_float(v.z << 16), c5 = __uint_as_float(v.z & 0xffff0000u);
    float c6 = __uint_as_float(v.w << 16), c7 = __uint_as_float(v.w & 0xffff0000u);
    unsigned lo = PK_FP8(c0, c1, 0u, false);
    lo = PK_FP8(c2, c3, lo, true);
    unsigned hi = PK_FP8(c4, c5, 0u, false);
    hi = PK_FP8(c6, c7, hi, true);
    h1f8[i] = make_uint2(lo, hi);
}

// ---- scatter edges into fixed-capacity dst buckets; 4B packed records ----
// rec = (dst&255)<<17 | src   (src < 2^17)
__global__ __launch_bounds__(256)
void bin_scatter_kernel(const int* __restrict__ src, const int* __restrict__ dst,
                        int* __restrict__ cursor, unsigned* __restrict__ binned) {
    __shared__ int cnt[NBUCKETS];
    __shared__ int base[NBUCKETS];
    int chunkBase = blockIdx.x * CHUNK;
    for (int i = threadIdx.x; i < NBUCKETS; i += 256) cnt[i] = 0;
    __syncthreads();
    int es[16], ed[16], lofs[16];
    #pragma unroll
    for (int j = 0; j < 16; ++j) {
        int e = chunkBase + j * 256 + threadIdx.x;
        if (e < N_EDGES) {
            es[j] = src[e];
            ed[j] = dst[e];
            lofs[j] = atomicAdd(&cnt[ed[j] >> 8], 1);
        }
    }
    __syncthreads();
    for (int i = threadIdx.x; i < NBUCKETS; i += 256) {
        int c = cnt[i];
        base[i] = c ? atomicAdd(&cursor[i], c) : 0;
    }
    __syncthreads();
    #pragma unroll
    for (int j = 0; j < 16; ++j) {
        int e = chunkBase + j * 256 + threadIdx.x;
        if (e < N_EDGES) {
            int b = ed[j] >> 8;
            int pos = base[b] + lofs[j];
            if (pos < (b + 1) * CAP)            // capacity guard (never hit at 12 sigma)
                binned[pos] = ((unsigned)(ed[j] & 255) << 17) | (unsigned)es[j];
        }
    }
}

// One block per bucket (256 nodes), single pass: records + ranks in registers.
// Adds an in-bucket degree counting-sort (LDS only, no global atomics):
// perm[b*256 + rank] = node, rank by degree within the bucket. Keeps perm
// bucket-contiguous so the aggregate XCD swizzle's L2 bucket-locality is
// preserved (R9 lesson: global sort destroyed it).
__global__ __launch_bounds__(256)
void bucket_build_kernel(const unsigned* __restrict__ binned, const int* __restrict__ cursor,
                         int2* __restrict__ row_info, int* __restrict__ src_sorted,
                         int* __restrict__ perm) {
    __shared__ int scnt[256];
    __shared__ int sscan[256];
    __shared__ int dh[64];
    __shared__ int db[64];
    int b = blockIdx.x;
    int t = threadIdx.x;
    int lo = b * CAP;
    int hi = cursor[b];
    int cap_end = lo + CAP;
    if (hi > cap_end) hi = cap_end;
    scnt[t] = 0;
    if (t < 64) dh[t] = 0;
    __syncthreads();
    unsigned rec[19];
    short rnk[19];
    #pragma unroll
    for (int i = 0; i < 19; ++i) {
        int e = lo + t + i * 256;
        if (e < hi) {
            unsigned r = binned[e];
            rec[i] = r;
            rnk[i] = (short)atomicAdd(&scnt[r >> 17], 1);
        }
    }
    __syncthreads();
    int v = scnt[t];
    sscan[t] = v;
    __syncthreads();
    for (int off = 1; off < 256; off <<= 1) {
        int a = (t >= off) ? sscan[t - off] : 0;
        __syncthreads();
        sscan[t] += a;
        __syncthreads();
    }
    int ex = sscan[t] - v;
    int node = b * 256 + t;
    int bin = 0, lr = 0;
    bool valid = node < N_NODES;
    if (valid) {
        row_info[node] = make_int2(lo + ex, v);
        bin = v < 63 ? v : 63;
        lr = atomicAdd(&dh[bin], 1);            // LDS: count AND rank-in-bin
    }
    scnt[t] = ex;
    __syncthreads();
    if (t < 64) db[t] = dh[t];
    __syncthreads();
    for (int off = 1; off < 64; off <<= 1) {    // inclusive scan over 64 bins
        int a = (t < 64 && t >= off) ? db[t - off] : 0;
        __syncthreads();
        if (t < 64) db[t] += a;
        __syncthreads();
    }
    if (valid)
        perm[b * 256 + (db[bin] - dh[bin]) + lr] = node;   // excl. prefix + rank
    #pragma unroll
    for (int i = 0; i < 19; ++i) {
        int e = lo + t + i * 256;
        if (e < hi) {
            unsigned r = rec[i];
            src_sorted[lo + scnt[r >> 17] + rnk[i]] = (int)(r & 0x1FFFFu);
        }
    }
}

// ---- mean aggregation from fp8 table ----
// 4 nodes per wave via in-bucket degree-sorted perm; T1 XCD swizzle keeps
// each bucket's src working set on one XCD's L2. 16-lane group per node,
// lane owns 8 channels. Out-of-degree rounds cndmask-redirect to the zeroed
// dummy row N_NODES. 4-deep gather ILP + next index-vector prefetch.
__global__ __launch_bounds__(256)
void aggregate_kernel(const unsigned char* __restrict__ feat8,
                      const int* __restrict__ src_sorted,
                      const int2* __restrict__ row_info,
                      const int* __restrict__ perm,
                      unsigned short* __restrict__ aggout) {
    int bid = blockIdx.x;
    int xcd = bid & 7;
    int idx = bid >> 3;
    int lb  = (xcd < 2) ? xcd * 782 + idx : 1564 + (xcd - 2) * 781 + idx;
    int tid  = threadIdx.x;
    int wave = tid >> 6;
    int lane = tid & 63;
    int l16  = lane & 15;                       // channel octet within row
    int grpbase = lane & 48;                    // (lane>>4)*16
    int node = perm[lb * 16 + wave * 4 + (lane >> 4)];     // 6250*16 = 100000
    int2 ri = row_info[node];
    int s = ri.x, deg = ri.y;
    // wave-uniform max degree across the 4 groups (near-equal after sort)
    int dmax = deg;
    dmax = max(dmax, __shfl_xor(dmax, 16, 64));
    dmax = max(dmax, __shfl_xor(dmax, 32, 64));
    unsigned chb = (unsigned)l16 * 8;           // byte offset within 128B row
    f32x2 a0[4], a1[4], a2[4], a3[4];
    #pragma unroll
    for (int i = 0; i < 4; ++i) {
        a0[i] = (f32x2){0.f, 0.f}; a1[i] = (f32x2){0.f, 0.f};
        a2[i] = (f32x2){0.f, 0.f}; a3[i] = (f32x2){0.f, 0.f};
    }

    int si = src_sorted[s + l16];               // first 16 edges (slack-padded)
    for (int c0 = 0; c0 < dmax; c0 += 16) {
        int si_next = si;
        if (c0 + 16 < dmax)                     // wave-uniform; rides under rounds
            si_next = src_sorted[s + c0 + 16 + l16];
        int rel = deg - c0;                     // per-lane valid-round bound
        int rend = dmax - c0; if (rend > 16) rend = 16;
        int r = 0;
        for (; r + 4 <= rend; r += 4) {         // 4 independent gathers in flight
            int u0 = __shfl(si, grpbase + r, 64);
            int u1 = __shfl(si, grpbase + r + 1, 64);
            int u2 = __shfl(si, grpbase + r + 2, 64);
            int u3 = __shfl(si, grpbase + r + 3, 64);
            u0 = (r < rel) ? u0 : N_NODES;
            u1 = (r + 1 < rel) ? u1 : N_NODES;
            u2 = (r + 2 < rel) ? u2 : N_NODES;
            u3 = (r + 3 < rel) ? u3 : N_NODES;
            uint2 v0 = *(const uint2*)(feat8 + (((unsigned)u0 << 7) + chb));
            uint2 v1 = *(const uint2*)(feat8 + (((unsigned)u1 << 7) + chb));
            uint2 v2 = *(const uint2*)(feat8 + (((unsigned)u2 << 7) + chb));
            uint2 v3 = *(const uint2*)(feat8 + (((unsigned)u3 << 7) + chb));
            a0[0] += UNPK_FP8(v0.x, false);
            a0[1] += UNPK_FP8(v0.x, true);
            a0[2] += UNPK_FP8(v0.y, false);
            a0[3] += UNPK_FP8(v0.y, true);
            a1[0] += UNPK_FP8(v1.x, false);
            a1[1] += UNPK_FP8(v1.x, true);
            a1[2] += UNPK_FP8(v1.y, false);
            a1[3] += UNPK_FP8(v1.y, true);
            a2[0] += UNPK_FP8(v2.x, false);
            a2[1] += UNPK_FP8(v2.x, true);
            a2[2] += UNPK_FP8(v2.y, false);
            a2[3] += UNPK_FP8(v2.y, true);
            a3[0] += UNPK_FP8(v3.x, false);
            a3[1] += UNPK_FP8(v3.x, true);
            a3[2] += UNPK_FP8(v3.y, false);
            a3[3] += UNPK_FP8(v3.y, true);
        }
        for (; r + 2 <= rend; r += 2) {
            int u0 = __shfl(si, grpbase + r, 64);
            int u1 = __shfl(si, grpbase + r + 1, 64);
            u0 = (r < rel) ? u0 : N_NODES;
            u1 = (r + 1 < rel) ? u1 : N_NODES;
            uint2 v0 = *(const uint2*)(feat8 + (((unsigned)u0 << 7) + chb));
            uint2 v1 = *(const uint2*)(feat8 + (((unsigned)u1 << 7) + chb));
            a0[0] += UNPK_FP8(v0.x, false);
            a0[1] += UNPK_FP8(v0.x, true);
            a0[2] += UNPK_FP8(v0.y, false);
            a0[3] += UNPK_FP8(v0.y, true);
            a1[0] += UNPK_FP8(v1.x, false);
            a1[1] += UNPK_FP8(v1.x, true);
            a1[2] += UNPK_FP8(v1.y, false);
            a1[3] += UNPK_FP8(v1.y, true);
        }
        if (r < rend) {
            int u0 = __shfl(si, grpbase + r, 64);
            u0 = (r < rel) ? u0 : N_NODES;
            uint2 v0 = *(const uint2*)(feat8 + (((unsigned)u0 << 7) + chb));
            a0[0] += UNPK_FP8(v0.x, false);
            a0[1] += UNPK_FP8(v0.x, true);
            a0[2] += UNPK_FP8(v0.y, false);
            a0[3] += UNPK_FP8(v0.y, true);
        }
        si = si_next;
    }
    float inv = 1.f / (float)(deg > 1 ? deg : 1);
    f32x2 t0 = ((a0[0] + a1[0]) + (a2[0] + a3[0])) * inv;
    f32x2 t1 = ((a0[1] + a1[1]) + (a2[1] + a3[1])) * inv;
    f32x2 t2 = ((a0[2] + a1[2]) + (a2[2] + a3[2])) * inv;
    f32x2 t3 = ((a0[3] + a1[3]) + (a2[3] + a3[3])) * inv;
    uint4 o;
    o.x = (unsigned)f2bf(t0.x) | ((unsigned)f2bf(t0.y) << 16);
    o.y = (unsigned)f2bf(t1.x) | ((unsigned)f2bf(t1.y) << 16);
    o.z = (unsigned)f2bf(t2.x) | ((unsigned)f2bf(t2.y) << 16);
    o.w = (unsigned)f2bf(t3.x) | ((unsigned)f2bf(t3.y) << 16);
    *(uint4*)(aggout + (size_t)node * 128 + l16 * 8) = o;
}

// ---- fused SAGE linear: relu([A1|A2]@Wcat^T+b), bf16 MFMA ----
// T3+T4: 2-phase double-buffer with COUNTED vmcnt (R12). STAGE issues 3
// global_load_lds per wave per chunk; after STAGE(kc+1), s_waitcnt vmcnt(3)
// retires exactly chunk kc's 3 loads (oldest) while kc+1's stay in flight
// across the barrier -- no full drain per chunk (the __syncthreads version's
// implicit vmcnt(0) drained the fresh loads every chunk). Raw s_barrier via
// asm with "memory" clobber = compiler fence (ds_reads can't hoist above).
// Each wave waits its OWN loads; the barrier joins all waves -> tile resident.
__global__ __launch_bounds__(256)
void gemm_kernel(const unsigned short* __restrict__ A1,   // k 0..127   (agg)
                 const unsigned short* __restrict__ A2,   // k 128..255 (self)
                 const unsigned short* __restrict__ Wcat, // [128 cols][256 k] bf16
                 const float* __restrict__ bias,
                 unsigned short* __restrict__ out) {
    __shared__ unsigned char sm[2][12288];    // [buf][A 4KB | W 8KB]
    int tid  = threadIdx.x;
    int w    = tid >> 6;
    int lane = tid & 63;
    int quad = lane >> 4, m = lane & 15;
    int nodeBase = blockIdx.x * 64;
    int gm = (m & 3) ^ ((m >> 2) & 3);        // per-thread read-swizzle constant
    int qo = ((quad ^ gm) & 3) * 16;          // swizzled 16B-unit byte offset

    int arow = w * 16 + (lane >> 2);
    int ga   = (arow & 3) ^ ((arow >> 2) & 3);
    int ua   = (lane & 3) ^ ga;
    int ra   = nodeBase + arow; if (ra > N_NODES - 1) ra = N_NODES - 1;
    int col0 = w * 32 + (lane >> 2);
    int col1 = col0 + 16;
    int u0 = (lane & 3) ^ ((col0 & 3) ^ ((col0 >> 2) & 3));
    int u1 = (lane & 3) ^ ((col1 & 3) ^ ((col1 >> 2) & 3));
    const char* a1c = (const char*)A1;
    const char* a2c = (const char*)A2;
    const char* wcc = (const char*)Wcat;

    floatx4 acc[4][2];
    #pragma unroll
    for (int a = 0; a < 4; ++a)
        #pragma unroll
        for (int b = 0; b < 2; ++b) acc[a][b] = (floatx4){0.f, 0.f, 0.f, 0.f};

#define STAGE(kc, buf) do {                                                      \
        const char* asrc = ((kc) < 4) ? a1c : a2c;                               \
        int kb = ((kc) & 3) * 64;                                               \
        GLOAD16(asrc + (size_t)ra * 256 + kb + ua * 16, &sm[buf][w * 1024]);     \
        int kw = (kc) * 64;                                                     \
        GLOAD16(wcc + (size_t)col0 * 512 + kw + u0 * 16, &sm[buf][4096 + (w*2)*1024]);     \
        GLOAD16(wcc + (size_t)col1 * 512 + kw + u1 * 16, &sm[buf][4096 + (w*2+1)*1024]);   \
    } while (0)

    STAGE(0, 0);
    #pragma unroll
    for (int kc = 0; kc < 8; ++kc) {
        int buf = kc & 1;
        if (kc < 7) {
            STAGE(kc + 1, buf ^ 1);           // issue next chunk first
            asm volatile("s_waitcnt vmcnt(3)" ::: "memory");  // kc done; kc+1 in flight
        } else {
            asm volatile("s_waitcnt vmcnt(0)" ::: "memory");
        }
        asm volatile("s_barrier" ::: "memory");   // all waves' kc data resident
        const char* As = (const char*)&sm[buf][0];
        const char* Ws = (const char*)&sm[buf][4096];
        short8 afr[4], bfr[2];
        #pragma unroll
        for (int nb = 0; nb < 4; ++nb)
            afr[nb] = *(const short8*)(As + (nb * 16 + m) * 64 + qo);
        #pragma unroll
        for (int cb = 0; cb < 2; ++cb)
            bfr[cb] = *(const short8*)(Ws + (w * 32 + cb * 16 + m) * 64 + qo);
        #pragma unroll
        for (int nb = 0; nb < 4; ++nb)
            #pragma unroll
            for (int cb = 0; cb < 2; ++cb)
                acc[nb][cb] = __builtin_amdgcn_mfma_f32_16x16x32_bf16(afr[nb], bfr[cb], acc[nb][cb], 0, 0, 0);
        if (kc < 7)
            asm volatile("s_barrier" ::: "memory");  // all waves done reading buf
    }
#undef STAGE

    #pragma unroll
    for (int cb = 0; cb < 2; ++cb) {
        int col = w * 32 + cb * 16 + m;
        float bv = bias[col];
        #pragma unroll
        for (int nb = 0; nb < 4; ++nb) {
            #pragma unroll
            for (int rr = 0; rr < 4; ++rr) {
                int row = nodeBase + nb * 16 + quad * 4 + rr;
                if (row < N_NODES) {
                    float v = acc[nb][cb][rr] + bv;
                    v = v > 0.f ? v : 0.f;
                    out[(size_t)row * 128 + col] = f2bf(v);
                }
            }
        }
    }
}

// ---- global_add_pool + LayerNorm + linear head (vectorized loads) ----
__global__ __launch_bounds__(256)
void pool_ln_out_kernel(const unsigned short* __restrict__ h2,
                        const int* __restrict__ batch,
                        const float* __restrict__ ln_g, const float* __restrict__ ln_b,
                        const float* __restrict__ Wlin, const float* __restrict__ blin,
                        float* __restrict__ out) {
    int g = blockIdx.x;
    int t = threadIdx.x;   // 256 threads
    int lane = t & 63, w = t >> 6;
    __shared__ int se[2];
    if (t < 2) {
        int target = g + t;
        int lo = 0, hi = N_NODES;
        while (lo < hi) {
            int mid = (lo + hi) >> 1;
            if (batch[mid] < target) lo = mid + 1; else hi = mid;
        }
        se[t] = lo;
    }
    __syncthreads();
    int s = se[0], e = se[1];
    int ns = t >> 4;       // 0..15 node stripe
    int chg = t & 15;      // channel group (8 ch)
    f32x2 a[4];
    a[0] = a[1] = a[2] = a[3] = (f32x2){0.f, 0.f};
    for (int n = s + ns; n < e; n += 16) {
        uint4 v = *(const uint4*)(h2 + (size_t)n * 128 + chg * 8);
        acc4(a, v);
    }
    #pragma unroll
    for (int i = 0; i < 4; ++i) {
        a[i].x += __shfl_xor(a[i].x, 16, 64);
        a[i].y += __shfl_xor(a[i].y, 16, 64);
        a[i].x += __shfl_xor(a[i].x, 32, 64);
        a[i].y += __shfl_xor(a[i].y, 32, 64);
    }
    __shared__ float sw[4][128];
    if (lane < 16) {
        #pragma unroll
        for (int k = 0; k < 4; ++k) {
            sw[w][chg * 8 + 2 * k]     = a[k].x;
            sw[w][chg * 8 + 2 * k + 1] = a[k].y;
        }
    }
    __syncthreads();
    __shared__ float red[128];
    float sum = 0.f;
    if (t < 128) {
        sum = sw[0][t] + sw[1][t] + sw[2][t] + sw[3][t];
        red[t] = sum;
    }
    __syncthreads();
    for (int off = 64; off > 0; off >>= 1) {
        if (t < off) red[t] += red[t + off];
        __syncthreads();
    }
    float mu = red[0] * (1.f / 128.f);
    __syncthreads();
    float dv = sum - mu;
    if (t < 128) red[t] = dv * dv;
    __syncthreads();
    for (int off = 64; off > 0; off >>= 1) {
        if (t < off) red[t] += red[t + off];
        __syncthreads();
    }
    float var = red[0] * (1.f / 128.f);
    __syncthreads();
    __shared__ float r0[128], r1[128];
    if (t < 128) {
        float gn = dv * rsqrtf(var + LN_EPS) * ln_g[t] + ln_b[t];
        r0[t] = gn * Wlin[t];
        r1[t] = gn * Wlin[128 + t];
    }
    __syncthreads();
    for (int off = 64; off > 0; off >>= 1) {
        if (t < off) { r0[t] += r0[t + off]; r1[t] += r1[t + off]; }
        __syncthreads();
    }
    if (t == 0) {
        out[g * 2 + 0] = r0[0] + blin[0];
        out[g * 2 + 1] = r1[0] + blin[1];
    }
}

extern "C" void kernel_launch(void* const* d_in, const int* in_sizes, int n_in,
                              void* d_out, int out_size, void* d_ws, size_t ws_size,
                              hipStream_t stream) {
    const float* x    = (const float*)d_in[0];
    const int*   ei   = (const int*)d_in[1];
    const int*   batch= (const int*)d_in[2];
    const float* W1l  = (const float*)d_in[3];
    const float* b1l  = (const float*)d_in[4];
    const float* W1r  = (const float*)d_in[5];
    const float* W2l  = (const float*)d_in[6];
    const float* b2l  = (const float*)d_in[7];
    const float* W2r  = (const float*)d_in[8];
    const float* ln_g = (const float*)d_in[9];
    const float* ln_b = (const float*)d_in[10];
    const float* Wlin = (const float*)d_in[11];
    const float* blin = (const float*)d_in[12];
    float* out = (float*)d_out;

    char* ws = (char*)d_ws;
    size_t off = 0;
    auto alloc = [&](size_t bytes) {
        char* p = ws + off;
        off = (off + bytes + 255) & ~(size_t)255;
        return p;
    };
    unsigned short* xbf  = (unsigned short*)alloc((size_t)N_NODES * D * 2); // later reused for h2
    unsigned short* aggb = (unsigned short*)alloc((size_t)N_NODES * D * 2); // aliased by binned
    unsigned short* h1   = (unsigned short*)alloc((size_t)N_NODES * D * 2);
    unsigned*       xf8  = (unsigned*)alloc((size_t)N_NODES * D + 128);     // fp8 x table (+dummy row); reused as h1f8
    unsigned short* Wc1  = (unsigned short*)alloc(128 * 256 * 2);
    unsigned short* Wc2  = (unsigned short*)alloc(128 * 256 * 2);
    int2* row_info   = (int2*)alloc((size_t)N_NODES * 8);
    int* src_sorted  = (int*)alloc(((size_t)NBUCKETS * CAP + 8192) * 4);    // +slack for unguarded preloads
    int* cursor      = (int*)alloc(NBUCKETS * 4);
    int* perm        = (int*)alloc((size_t)N_NODES * 4);
    unsigned* binned = (unsigned*)aggb;   // 7.6 MB <= 25.6 MB; consumed before aggb written
    uint2* h1f8      = (uint2*)xf8;       // xf8 dead after aggregate1 (dummy row stays zeroed)

    const int* srcI = ei;            // edge_index[0]
    const int* dstI = ei + N_EDGES;  // edge_index[1]

    prep_kernel<<<12500, 256, 0, stream>>>(x, xbf, xf8, W1l, W1r, W2l, W2r, Wc1, Wc2, cursor);
    bin_scatter_kernel<<<(N_EDGES + CHUNK - 1) / CHUNK, 256, 0, stream>>>(srcI, dstI, cursor, binned);
    bucket_build_kernel<<<NBUCKETS, 256, 0, stream>>>(binned, cursor, row_info, src_sorted, perm);

    aggregate_kernel<<<6250, 256, 0, stream>>>((const unsigned char*)xf8, src_sorted, row_info, perm, aggb);
    gemm_kernel<<<1563, 256, 0, stream>>>(aggb, xbf, Wc1, b1l, h1);
    cvt_h1_kernel<<<6250, 256, 0, stream>>>(h1, h1f8);
    aggregate_kernel<<<6250, 256, 0, stream>>>((const unsigned char*)h1f8, src_sorted, row_info, perm, aggb);
    gemm_kernel<<<1563, 256, 0, stream>>>(aggb, h1, Wc2, b2l, xbf);
    pool_ln_out_kernel<<<NUM_GRAPHS, 256, 0, stream>>>(xbf, batch, ln_g, ln_b, Wlin, blin, out);
}

// Round 13
// 270.213 us; speedup vs baseline: 2.9883x; 1.0422x over previous
//
#include <hip/hip_runtime.h>
#include <hip/hip_bf16.h>
#include <hip/hip_fp8.h>

#define N_NODES   100000
#define N_EDGES   1600000
#define NUM_GRAPHS 1024
#define D         128
#define LN_EPS    1e-5f
#define NBUCKETS  391     // buckets of 256 nodes: bucket = dst >> 8
#define CAP       4864    // fixed bucket capacity (mean 4096 + 12 sigma); CAP/256 = 19
#define CHUNK     4096    // edges per bin_scatter block

typedef __attribute__((ext_vector_type(8))) short short8;
typedef __attribute__((ext_vector_type(4))) float floatx4;
typedef __attribute__((ext_vector_type(2))) float f32x2;

static __device__ __forceinline__ unsigned short f2bf(float f) {
    __hip_bfloat16 h = __float2bfloat16(f);
    return *reinterpret_cast<unsigned short*>(&h);
}
static __device__ __forceinline__ unsigned char fp8b(float v) {
    __hip_fp8_e4m3 t = (__hip_fp8_e4m3)v;
    return *reinterpret_cast<unsigned char*>(&t);
}
// accumulate 8 bf16 channels (one uint4) into 4 packed fp32 pairs
static __device__ __forceinline__ void acc4(f32x2* acc, uint4 v) {
    acc[0] += (f32x2){__uint_as_float(v.x << 16), __uint_as_float(v.x & 0xffff0000u)};
    acc[1] += (f32x2){__uint_as_float(v.y << 16), __uint_as_float(v.y & 0xffff0000u)};
    acc[2] += (f32x2){__uint_as_float(v.z << 16), __uint_as_float(v.z & 0xffff0000u)};
    acc[3] += (f32x2){__uint_as_float(v.w << 16), __uint_as_float(v.w & 0xffff0000u)};
}

// ---- fp8 e4m3 (OCP) pack/unpack ----
#if __has_builtin(__builtin_amdgcn_cvt_pk_f32_fp8)
#define UNPK_FP8(x, w) __builtin_amdgcn_cvt_pk_f32_fp8((x), (w))
#else
static __device__ __forceinline__ f32x2 unpk_fp8_sw(unsigned x, bool w) {
    unsigned s = w ? (x >> 16) : (x & 0xffffu);
    __hip_fp8_e4m3 a, b;
    *reinterpret_cast<unsigned char*>(&a) = (unsigned char)(s & 0xff);
    *reinterpret_cast<unsigned char*>(&b) = (unsigned char)((s >> 8) & 0xff);
    return (f32x2){(float)a, (float)b};
}
#define UNPK_FP8(x, w) unpk_fp8_sw((x), (w))
#endif

#if __has_builtin(__builtin_amdgcn_cvt_pk_fp8_f32)
#define PK_FP8(a, b, old, w) ((unsigned)__builtin_amdgcn_cvt_pk_fp8_f32((a), (b), (int)(old), (w)))
#else
static __device__ __forceinline__ unsigned pk_fp8_sw(float a, float b) {
    __hip_fp8_e4m3 fa = (__hip_fp8_e4m3)a;
    __hip_fp8_e4m3 fb = (__hip_fp8_e4m3)b;
    return (unsigned)*reinterpret_cast<unsigned char*>(&fa) |
           ((unsigned)*reinterpret_cast<unsigned char*>(&fb) << 8);
}
#define PK_FP8(a, b, old, w) ((w) ? ((((unsigned)(old)) & 0xffffu) | (pk_fp8_sw((a),(b)) << 16)) \
                                  : ((((unsigned)(old)) & 0xffff0000u) | pk_fp8_sw((a),(b))))
#endif

// async 16B global->LDS; lds ptr must be wave-uniform base (HW adds lane*16)
#define GLOAD16(g, l) __builtin_amdgcn_global_load_lds( \
    (const __attribute__((address_space(1))) void*)(g), \
    (__attribute__((address_space(3))) void*)(l), 16, 0, 0)

// ---- fused prep: x -> bf16 + fp8 tables, weight concat+cvt, cursor init ----
__global__ __launch_bounds__(256)
void prep_kernel(const float* __restrict__ x, unsigned short* __restrict__ xbf,
                 unsigned* __restrict__ xf8,
                 const float* __restrict__ W1l, const float* __restrict__ W1r,
                 const float* __restrict__ W2l, const float* __restrict__ W2r,
                 unsigned short* __restrict__ Wc1, unsigned short* __restrict__ Wc2,
                 int* __restrict__ cursor) {
    int i = blockIdx.x * 256 + threadIdx.x;     // float4 index, 3.2M exact
    float4 v = reinterpret_cast<const float4*>(x)[i];
    ushort4 o;
    o.x = f2bf(v.x); o.y = f2bf(v.y); o.z = f2bf(v.z); o.w = f2bf(v.w);
    reinterpret_cast<ushort4*>(xbf)[i] = o;
    unsigned p = PK_FP8(v.x, v.y, 0u, false);
    p = PK_FP8(v.z, v.w, p, true);
    xf8[i] = p;                                 // 4 fp8 bytes, coalesced
    if (blockIdx.x < 256) {                     // 65536 weight elements
        int layer = i >> 15;
        int rem = i & 32767;
        int c = rem >> 8;
        int k = rem & 255;
        const float* Wl = layer ? W2l : W1l;
        const float* Wr = layer ? W2r : W1r;
        unsigned short* dst = layer ? Wc2 : Wc1;
        float wv = (k < 128) ? Wl[c * 128 + k] : Wr[c * 128 + (k - 128)];
        dst[c * 256 + k] = f2bf(wv);
    }
    if (blockIdx.x == 256) {
        for (int b = threadIdx.x; b < NBUCKETS; b += 256)
            cursor[b] = b * CAP;
        // zero dummy row N_NODES of the fp8 table (degree padding target)
        if (threadIdx.x < 32)
            xf8[(size_t)N_NODES * 32 + threadIdx.x] = 0u;
    }
}

// ---- scatter edges into fixed-capacity dst buckets; 4B packed records ----
// rec = (dst&255)<<17 | src   (src < 2^17)
__global__ __launch_bounds__(256)
void bin_scatter_kernel(const int* __restrict__ src, const int* __restrict__ dst,
                        int* __restrict__ cursor, unsigned* __restrict__ binned) {
    __shared__ int cnt[NBUCKETS];
    __shared__ int base[NBUCKETS];
    int chunkBase = blockIdx.x * CHUNK;
    for (int i = threadIdx.x; i < NBUCKETS; i += 256) cnt[i] = 0;
    __syncthreads();
    int es[16], ed[16], lofs[16];
    #pragma unroll
    for (int j = 0; j < 16; ++j) {
        int e = chunkBase + j * 256 + threadIdx.x;
        if (e < N_EDGES) {
            es[j] = src[e];
            ed[j] = dst[e];
            lofs[j] = atomicAdd(&cnt[ed[j] >> 8], 1);
        }
    }
    __syncthreads();
    for (int i = threadIdx.x; i < NBUCKETS; i += 256) {
        int c = cnt[i];
        base[i] = c ? atomicAdd(&cursor[i], c) : 0;
    }
    __syncthreads();
    #pragma unroll
    for (int j = 0; j < 16; ++j) {
        int e = chunkBase + j * 256 + threadIdx.x;
        if (e < N_EDGES) {
            int b = ed[j] >> 8;
            int pos = base[b] + lofs[j];
            if (pos < (b + 1) * CAP)            // capacity guard (never hit at 12 sigma)
                binned[pos] = ((unsigned)(ed[j] & 255) << 17) | (unsigned)es[j];
        }
    }
}

// One block per bucket (256 nodes), single pass: records + ranks in registers.
// Adds an in-bucket degree counting-sort (LDS only, no global atomics):
// perm[b*256 + rank] = node, rank by degree within the bucket. Keeps perm
// bucket-contiguous so the aggregate XCD swizzle's L2 bucket-locality is
// preserved (R9 lesson: global sort destroyed it).
__global__ __launch_bounds__(256)
void bucket_build_kernel(const unsigned* __restrict__ binned, const int* __restrict__ cursor,
                         int2* __restrict__ row_info, int* __restrict__ src_sorted,
                         int* __restrict__ perm) {
    __shared__ int scnt[256];
    __shared__ int sscan[256];
    __shared__ int dh[64];
    __shared__ int db[64];
    int b = blockIdx.x;
    int t = threadIdx.x;
    int lo = b * CAP;
    int hi = cursor[b];
    int cap_end = lo + CAP;
    if (hi > cap_end) hi = cap_end;
    scnt[t] = 0;
    if (t < 64) dh[t] = 0;
    __syncthreads();
    unsigned rec[19];
    short rnk[19];
    #pragma unroll
    for (int i = 0; i < 19; ++i) {
        int e = lo + t + i * 256;
        if (e < hi) {
            unsigned r = binned[e];
            rec[i] = r;
            rnk[i] = (short)atomicAdd(&scnt[r >> 17], 1);
        }
    }
    __syncthreads();
    int v = scnt[t];
    sscan[t] = v;
    __syncthreads();
    for (int off = 1; off < 256; off <<= 1) {
        int a = (t >= off) ? sscan[t - off] : 0;
        __syncthreads();
        sscan[t] += a;
        __syncthreads();
    }
    int ex = sscan[t] - v;
    int node = b * 256 + t;
    int bin = 0, lr = 0;
    bool valid = node < N_NODES;
    if (valid) {
        row_info[node] = make_int2(lo + ex, v);
        bin = v < 63 ? v : 63;
        lr = atomicAdd(&dh[bin], 1);            // LDS: count AND rank-in-bin
    }
    scnt[t] = ex;
    __syncthreads();
    if (t < 64) db[t] = dh[t];
    __syncthreads();
    for (int off = 1; off < 64; off <<= 1) {    // inclusive scan over 64 bins
        int a = (t < 64 && t >= off) ? db[t - off] : 0;
        __syncthreads();
        if (t < 64) db[t] += a;
        __syncthreads();
    }
    if (valid)
        perm[b * 256 + (db[bin] - dh[bin]) + lr] = node;   // excl. prefix + rank
    #pragma unroll
    for (int i = 0; i < 19; ++i) {
        int e = lo + t + i * 256;
        if (e < hi) {
            unsigned r = rec[i];
            src_sorted[lo + scnt[r >> 17] + rnk[i]] = (int)(r & 0x1FFFFu);
        }
    }
}

// ---- mean aggregation from fp8 table ----
// 4 nodes per wave via in-bucket degree-sorted perm; T1 XCD swizzle keeps
// each bucket's src working set on one XCD's L2. 16-lane group per node,
// lane owns 8 channels. Out-of-degree rounds cndmask-redirect to the zeroed
// dummy row N_NODES. 4-deep gather ILP + next index-vector prefetch.
__global__ __launch_bounds__(256)
void aggregate_kernel(const unsigned char* __restrict__ feat8,
                      const int* __restrict__ src_sorted,
                      const int2* __restrict__ row_info,
                      const int* __restrict__ perm,
                      unsigned short* __restrict__ aggout) {
    int bid = blockIdx.x;
    int xcd = bid & 7;
    int idx = bid >> 3;
    int lb  = (xcd < 2) ? xcd * 782 + idx : 1564 + (xcd - 2) * 781 + idx;
    int tid  = threadIdx.x;
    int wave = tid >> 6;
    int lane = tid & 63;
    int l16  = lane & 15;                       // channel octet within row
    int grpbase = lane & 48;                    // (lane>>4)*16
    int node = perm[lb * 16 + wave * 4 + (lane >> 4)];     // 6250*16 = 100000
    int2 ri = row_info[node];
    int s = ri.x, deg = ri.y;
    // wave-uniform max degree across the 4 groups (near-equal after sort)
    int dmax = deg;
    dmax = max(dmax, __shfl_xor(dmax, 16, 64));
    dmax = max(dmax, __shfl_xor(dmax, 32, 64));
    unsigned chb = (unsigned)l16 * 8;           // byte offset within 128B row
    f32x2 a0[4], a1[4], a2[4], a3[4];
    #pragma unroll
    for (int i = 0; i < 4; ++i) {
        a0[i] = (f32x2){0.f, 0.f}; a1[i] = (f32x2){0.f, 0.f};
        a2[i] = (f32x2){0.f, 0.f}; a3[i] = (f32x2){0.f, 0.f};
    }

    int si = src_sorted[s + l16];               // first 16 edges (slack-padded)
    for (int c0 = 0; c0 < dmax; c0 += 16) {
        int si_next = si;
        if (c0 + 16 < dmax)                     // wave-uniform; rides under rounds
            si_next = src_sorted[s + c0 + 16 + l16];
        int rel = deg - c0;                     // per-lane valid-round bound
        int rend = dmax - c0; if (rend > 16) rend = 16;
        int r = 0;
        for (; r + 4 <= rend; r += 4) {         // 4 independent gathers in flight
            int u0 = __shfl(si, grpbase + r, 64);
            int u1 = __shfl(si, grpbase + r + 1, 64);
            int u2 = __shfl(si, grpbase + r + 2, 64);
            int u3 = __shfl(si, grpbase + r + 3, 64);
            u0 = (r < rel) ? u0 : N_NODES;
            u1 = (r + 1 < rel) ? u1 : N_NODES;
            u2 = (r + 2 < rel) ? u2 : N_NODES;
            u3 = (r + 3 < rel) ? u3 : N_NODES;
            uint2 v0 = *(const uint2*)(feat8 + (((unsigned)u0 << 7) + chb));
            uint2 v1 = *(const uint2*)(feat8 + (((unsigned)u1 << 7) + chb));
            uint2 v2 = *(const uint2*)(feat8 + (((unsigned)u2 << 7) + chb));
            uint2 v3 = *(const uint2*)(feat8 + (((unsigned)u3 << 7) + chb));
            a0[0] += UNPK_FP8(v0.x, false);
            a0[1] += UNPK_FP8(v0.x, true);
            a0[2] += UNPK_FP8(v0.y, false);
            a0[3] += UNPK_FP8(v0.y, true);
            a1[0] += UNPK_FP8(v1.x, false);
            a1[1] += UNPK_FP8(v1.x, true);
            a1[2] += UNPK_FP8(v1.y, false);
            a1[3] += UNPK_FP8(v1.y, true);
            a2[0] += UNPK_FP8(v2.x, false);
            a2[1] += UNPK_FP8(v2.x, true);
            a2[2] += UNPK_FP8(v2.y, false);
            a2[3] += UNPK_FP8(v2.y, true);
            a3[0] += UNPK_FP8(v3.x, false);
            a3[1] += UNPK_FP8(v3.x, true);
            a3[2] += UNPK_FP8(v3.y, false);
            a3[3] += UNPK_FP8(v3.y, true);
        }
        for (; r + 2 <= rend; r += 2) {
            int u0 = __shfl(si, grpbase + r, 64);
            int u1 = __shfl(si, grpbase + r + 1, 64);
            u0 = (r < rel) ? u0 : N_NODES;
            u1 = (r + 1 < rel) ? u1 : N_NODES;
            uint2 v0 = *(const uint2*)(feat8 + (((unsigned)u0 << 7) + chb));
            uint2 v1 = *(const uint2*)(feat8 + (((unsigned)u1 << 7) + chb));
            a0[0] += UNPK_FP8(v0.x, false);
            a0[1] += UNPK_FP8(v0.x, true);
            a0[2] += UNPK_FP8(v0.y, false);
            a0[3] += UNPK_FP8(v0.y, true);
            a1[0] += UNPK_FP8(v1.x, false);
            a1[1] += UNPK_FP8(v1.x, true);
            a1[2] += UNPK_FP8(v1.y, false);
            a1[3] += UNPK_FP8(v1.y, true);
        }
        if (r < rend) {
            int u0 = __shfl(si, grpbase + r, 64);
            u0 = (r < rel) ? u0 : N_NODES;
            uint2 v0 = *(const uint2*)(feat8 + (((unsigned)u0 << 7) + chb));
            a0[0] += UNPK_FP8(v0.x, false);
            a0[1] += UNPK_FP8(v0.x, true);
            a0[2] += UNPK_FP8(v0.y, false);
            a0[3] += UNPK_FP8(v0.y, true);
        }
        si = si_next;
    }
    float inv = 1.f / (float)(deg > 1 ? deg : 1);
    f32x2 t0 = ((a0[0] + a1[0]) + (a2[0] + a3[0])) * inv;
    f32x2 t1 = ((a0[1] + a1[1]) + (a2[1] + a3[1])) * inv;
    f32x2 t2 = ((a0[2] + a1[2]) + (a2[2] + a3[2])) * inv;
    f32x2 t3 = ((a0[3] + a1[3]) + (a2[3] + a3[3])) * inv;
    uint4 o;
    o.x = (unsigned)f2bf(t0.x) | ((unsigned)f2bf(t0.y) << 16);
    o.y = (unsigned)f2bf(t1.x) | ((unsigned)f2bf(t1.y) << 16);
    o.z = (unsigned)f2bf(t2.x) | ((unsigned)f2bf(t2.y) << 16);
    o.w = (unsigned)f2bf(t3.x) | ((unsigned)f2bf(t3.y) << 16);
    *(uint4*)(aggout + (size_t)node * 128 + l16 * 8) = o;
}

// ---- fused SAGE linear: relu([A1|A2]@Wcat^T+b), bf16 MFMA ----
// T3+T4 2-phase counted-vmcnt loop (R12-verified). Optional fp8 output via
// LDS-staged COALESCED flush (R13): bytes staged to an 8KB LDS tile after
// the K-loop, then written as full 128B rows (32B/lane uint4) -- avoids the
// scattered byte-store WRITE inflation that sank R2/R9's direct fusion.
template <bool F8OUT>
__global__ __launch_bounds__(256)
void gemm_kernel(const unsigned short* __restrict__ A1,   // k 0..127   (agg)
                 const unsigned short* __restrict__ A2,   // k 128..255 (self)
                 const unsigned short* __restrict__ Wcat, // [128 cols][256 k] bf16
                 const float* __restrict__ bias,
                 unsigned short* __restrict__ out,
                 unsigned char* __restrict__ f8out) {
    __shared__ unsigned char sm[2][12288];    // [buf][A 4KB | W 8KB]; buf0 reused for f8 stage
    int tid  = threadIdx.x;
    int w    = tid >> 6;
    int lane = tid & 63;
    int quad = lane >> 4, m = lane & 15;
    int nodeBase = blockIdx.x * 64;
    int gm = (m & 3) ^ ((m >> 2) & 3);        // per-thread read-swizzle constant
    int qo = ((quad ^ gm) & 3) * 16;          // swizzled 16B-unit byte offset

    int arow = w * 16 + (lane >> 2);
    int ga   = (arow & 3) ^ ((arow >> 2) & 3);
    int ua   = (lane & 3) ^ ga;
    int ra   = nodeBase + arow; if (ra > N_NODES - 1) ra = N_NODES - 1;
    int col0 = w * 32 + (lane >> 2);
    int col1 = col0 + 16;
    int u0 = (lane & 3) ^ ((col0 & 3) ^ ((col0 >> 2) & 3));
    int u1 = (lane & 3) ^ ((col1 & 3) ^ ((col1 >> 2) & 3));
    const char* a1c = (const char*)A1;
    const char* a2c = (const char*)A2;
    const char* wcc = (const char*)Wcat;

    floatx4 acc[4][2];
    #pragma unroll
    for (int a = 0; a < 4; ++a)
        #pragma unroll
        for (int b = 0; b < 2; ++b) acc[a][b] = (floatx4){0.f, 0.f, 0.f, 0.f};

#define STAGE(kc, buf) do {                                                      \
        const char* asrc = ((kc) < 4) ? a1c : a2c;                               \
        int kb = ((kc) & 3) * 64;                                               \
        GLOAD16(asrc + (size_t)ra * 256 + kb + ua * 16, &sm[buf][w * 1024]);     \
        int kw = (kc) * 64;                                                     \
        GLOAD16(wcc + (size_t)col0 * 512 + kw + u0 * 16, &sm[buf][4096 + (w*2)*1024]);     \
        GLOAD16(wcc + (size_t)col1 * 512 + kw + u1 * 16, &sm[buf][4096 + (w*2+1)*1024]);   \
    } while (0)

    STAGE(0, 0);
    #pragma unroll
    for (int kc = 0; kc < 8; ++kc) {
        int buf = kc & 1;
        if (kc < 7) {
            STAGE(kc + 1, buf ^ 1);           // issue next chunk first
            asm volatile("s_waitcnt vmcnt(3)" ::: "memory");  // kc done; kc+1 in flight
        } else {
            asm volatile("s_waitcnt vmcnt(0)" ::: "memory");
        }
        asm volatile("s_barrier" ::: "memory");   // all waves' kc data resident
        const char* As = (const char*)&sm[buf][0];
        const char* Ws = (const char*)&sm[buf][4096];
        short8 afr[4], bfr[2];
        #pragma unroll
        for (int nb = 0; nb < 4; ++nb)
            afr[nb] = *(const short8*)(As + (nb * 16 + m) * 64 + qo);
        #pragma unroll
        for (int cb = 0; cb < 2; ++cb)
            bfr[cb] = *(const short8*)(Ws + (w * 32 + cb * 16 + m) * 64 + qo);
        #pragma unroll
        for (int nb = 0; nb < 4; ++nb)
            #pragma unroll
            for (int cb = 0; cb < 2; ++cb)
                acc[nb][cb] = __builtin_amdgcn_mfma_f32_16x16x32_bf16(afr[nb], bfr[cb], acc[nb][cb], 0, 0, 0);
        if (kc < 7)
            asm volatile("s_barrier" ::: "memory");  // all waves done reading buf
    }
#undef STAGE

    unsigned char* f8s = &sm[0][0];           // 8KB fp8 stage [64 rows][128B]
    #pragma unroll
    for (int cb = 0; cb < 2; ++cb) {
        int col = w * 32 + cb * 16 + m;
        float bv = bias[col];
        #pragma unroll
        for (int nb = 0; nb < 4; ++nb) {
            #pragma unroll
            for (int rr = 0; rr < 4; ++rr) {
                int lr = nb * 16 + quad * 4 + rr;
                int row = nodeBase + lr;
                float v = acc[nb][cb][rr] + bv;
                v = v > 0.f ? v : 0.f;
                if (row < N_NODES)
                    out[(size_t)row * 128 + col] = f2bf(v);
                if (F8OUT)
                    f8s[lr * 128 + col] = fp8b(v);   // LDS byte stage
            }
        }
    }
    if (F8OUT) {
        __syncthreads();                       // f8 tile complete
        int lr = tid >> 2, sg = tid & 3;       // row, 32B segment
        int row = nodeBase + lr;
        if (row < N_NODES) {
            uint4 v0 = *(const uint4*)(f8s + lr * 128 + sg * 32);
            uint4 v1 = *(const uint4*)(f8s + lr * 128 + sg * 32 + 16);
            *(uint4*)(f8out + (size_t)row * 128 + sg * 32) = v0;
            *(uint4*)(f8out + (size_t)row * 128 + sg * 32 + 16) = v1;
        }
    }
}

// ---- global_add_pool + LayerNorm + linear head (vectorized loads) ----
__global__ __launch_bounds__(256)
void pool_ln_out_kernel(const unsigned short* __restrict__ h2,
                        const int* __restrict__ batch,
                        const float* __restrict__ ln_g, const float* __restrict__ ln_b,
                        const float* __restrict__ Wlin, const float* __restrict__ blin,
                        float* __restrict__ out) {
    int g = blockIdx.x;
    int t = threadIdx.x;   // 256 threads
    int lane = t & 63, w = t >> 6;
    __shared__ int se[2];
    if (t < 2) {
        int target = g + t;
        int lo = 0, hi = N_NODES;
        while (lo < hi) {
            int mid = (lo + hi) >> 1;
            if (batch[mid] < target) lo = mid + 1; else hi = mid;
        }
        se[t] = lo;
    }
    __syncthreads();
    int s = se[0], e = se[1];
    int ns = t >> 4;       // 0..15 node stripe
    int chg = t & 15;      // channel group (8 ch)
    f32x2 a[4];
    a[0] = a[1] = a[2] = a[3] = (f32x2){0.f, 0.f};
    for (int n = s + ns; n < e; n += 16) {
        uint4 v = *(const uint4*)(h2 + (size_t)n * 128 + chg * 8);
        acc4(a, v);
    }
    #pragma unroll
    for (int i = 0; i < 4; ++i) {
        a[i].x += __shfl_xor(a[i].x, 16, 64);
        a[i].y += __shfl_xor(a[i].y, 16, 64);
        a[i].x += __shfl_xor(a[i].x, 32, 64);
        a[i].y += __shfl_xor(a[i].y, 32, 64);
    }
    __shared__ float sw[4][128];
    if (lane < 16) {
        #pragma unroll
        for (int k = 0; k < 4; ++k) {
            sw[w][chg * 8 + 2 * k]     = a[k].x;
            sw[w][chg * 8 + 2 * k + 1] = a[k].y;
        }
    }
    __syncthreads();
    __shared__ float red[128];
    float sum = 0.f;
    if (t < 128) {
        sum = sw[0][t] + sw[1][t] + sw[2][t] + sw[3][t];
        red[t] = sum;
    }
    __syncthreads();
    for (int off = 64; off > 0; off >>= 1) {
        if (t < off) red[t] += red[t + off];
        __syncthreads();
    }
    float mu = red[0] * (1.f / 128.f);
    __syncthreads();
    float dv = sum - mu;
    if (t < 128) red[t] = dv * dv;
    __syncthreads();
    for (int off = 64; off > 0; off >>= 1) {
        if (t < off) red[t] += red[t + off];
        __syncthreads();
    }
    float var = red[0] * (1.f / 128.f);
    __syncthreads();
    __shared__ float r0[128], r1[128];
    if (t < 128) {
        float gn = dv * rsqrtf(var + LN_EPS) * ln_g[t] + ln_b[t];
        r0[t] = gn * Wlin[t];
        r1[t] = gn * Wlin[128 + t];
    }
    __syncthreads();
    for (int off = 64; off > 0; off >>= 1) {
        if (t < off) { r0[t] += r0[t + off]; r1[t] += r1[t + off]; }
        __syncthreads();
    }
    if (t == 0) {
        out[g * 2 + 0] = r0[0] + blin[0];
        out[g * 2 + 1] = r1[0] + blin[1];
    }
}

extern "C" void kernel_launch(void* const* d_in, const int* in_sizes, int n_in,
                              void* d_out, int out_size, void* d_ws, size_t ws_size,
                              hipStream_t stream) {
    const float* x    = (const float*)d_in[0];
    const int*   ei   = (const int*)d_in[1];
    const int*   batch= (const int*)d_in[2];
    const float* W1l  = (const float*)d_in[3];
    const float* b1l  = (const float*)d_in[4];
    const float* W1r  = (const float*)d_in[5];
    const float* W2l  = (const float*)d_in[6];
    const float* b2l  = (const float*)d_in[7];
    const float* W2r  = (const float*)d_in[8];
    const float* ln_g = (const float*)d_in[9];
    const float* ln_b = (const float*)d_in[10];
    const float* Wlin = (const float*)d_in[11];
    const float* blin = (const float*)d_in[12];
    float* out = (float*)d_out;

    char* ws = (char*)d_ws;
    size_t off = 0;
    auto alloc = [&](size_t bytes) {
        char* p = ws + off;
        off = (off + bytes + 255) & ~(size_t)255;
        return p;
    };
    unsigned short* xbf  = (unsigned short*)alloc((size_t)N_NODES * D * 2); // later reused for h2
    unsigned short* aggb = (unsigned short*)alloc((size_t)N_NODES * D * 2); // aliased by binned
    unsigned short* h1   = (unsigned short*)alloc((size_t)N_NODES * D * 2);
    unsigned*       xf8  = (unsigned*)alloc((size_t)N_NODES * D + 128);     // fp8 x table (+dummy row); reused as h1f8
    unsigned short* Wc1  = (unsigned short*)alloc(128 * 256 * 2);
    unsigned short* Wc2  = (unsigned short*)alloc(128 * 256 * 2);
    int2* row_info   = (int2*)alloc((size_t)N_NODES * 8);
    int* src_sorted  = (int*)alloc(((size_t)NBUCKETS * CAP + 8192) * 4);    // +slack for unguarded preloads
    int* cursor      = (int*)alloc(NBUCKETS * 4);
    int* perm        = (int*)alloc((size_t)N_NODES * 4);
    unsigned* binned = (unsigned*)aggb;   // 7.6 MB <= 25.6 MB; consumed before aggb written
    unsigned char* h1f8 = (unsigned char*)xf8;  // xf8 dead after aggregate1 (dummy row stays zeroed)

    const int* srcI = ei;            // edge_index[0]
    const int* dstI = ei + N_EDGES;  // edge_index[1]

    prep_kernel<<<12500, 256, 0, stream>>>(x, xbf, xf8, W1l, W1r, W2l, W2r, Wc1, Wc2, cursor);
    bin_scatter_kernel<<<(N_EDGES + CHUNK - 1) / CHUNK, 256, 0, stream>>>(srcI, dstI, cursor, binned);
    bucket_build_kernel<<<NBUCKETS, 256, 0, stream>>>(binned, cursor, row_info, src_sorted, perm);

    aggregate_kernel<<<6250, 256, 0, stream>>>((const unsigned char*)xf8, src_sorted, row_info, perm, aggb);
    gemm_kernel<true><<<1563, 256, 0, stream>>>(aggb, xbf, Wc1, b1l, h1, h1f8);
    aggregate_kernel<<<6250, 256, 0, stream>>>(h1f8, src_sorted, row_info, perm, aggb);
    gemm_kernel<false><<<1563, 256, 0, stream>>>(aggb, h1, Wc2, b2l, xbf, nullptr);
    pool_ln_out_kernel<<<NUM_GRAPHS, 256, 0, stream>>>(xbf, batch, ln_g, ln_b, Wlin, blin, out);
}